// Round 7
// baseline (300.286 us; speedup 1.0000x reference)
//
#include <hip/hip_runtime.h>
#include <math.h>

#define NN 50000
#define NE 800000
#define HD 128
#define NL 3
#define NG 64
#define BN_EPS 1e-5f
#define NB 196   // dst buckets of 256 nodes
#define EPB 4096 // edges per block in bucket scatter
#define NCNT ((NE + EPB - 1) / EPB)     // 196 scatter blocks
#define CAP 8192 // fixed bucket capacity (mean 4096 + 64 sigma)
#define WSTR 136 // LDS weight row stride (fp16 elems)
#define ASTR 136 // LDS aggregate row stride (fp16 elems; 272B = 17x16 keeps 16B align)
#define NREP 32  // stats replicas (TCC same-address contention /32)
#define GATHB ((NN * 16) / 256)         // 3125 cvt blocks (exact)
#define GEMMB ((NN + 63) / 64)          // 782 fused tiles

typedef _Float16 f16;
typedef __attribute__((ext_vector_type(8))) _Float16 f16x8;
typedef __attribute__((ext_vector_type(4))) float f32x4;

// BN affine from replicated raw sums
__device__ __forceinline__ void bn_affine(const float* __restrict__ sR, int c,
                                          const float* __restrict__ gam,
                                          const float* __restrict__ bet,
                                          float* sc, float* sh) {
    float s0 = 0.f, s1 = 0.f;
#pragma unroll 8
    for (int r = 0; r < NREP; ++r) {
        s0 += sR[r * 256 + c];
        s1 += sR[r * 256 + 128 + c];
    }
    float invN = 1.0f / (float)NN;
    float mu = s0 * invN;
    float var = s1 * invN - mu * mu;
    var = var < 0.f ? 0.f : var;
    float s = rsqrtf(var + BN_EPS) * gam[c];
    *sc = s;
    *sh = bet[c] - mu * s;
}

// weight prep body: BN-folded Wh (fp16) + folded bias2. One block per output ch j.
__device__ __forceinline__ void wprep_body(int j, int k, float* red,
                                           const float* __restrict__ statsPrev,
                                           const float* __restrict__ gamP,
                                           const float* __restrict__ betP,
                                           const float* __restrict__ Wl,
                                           const float* __restrict__ Wr,
                                           const float* __restrict__ bl,
                                           f16* __restrict__ Wh,
                                           float* __restrict__ bias2) {
    float scp = 1.0f, shp = 0.0f;
    if (statsPrev) bn_affine(statsPrev, k & 127, gamP, betP, &scp, &shp);
    float w = (k < HD) ? Wl[j * HD + k] : Wr[j * HD + (k - HD)];
    Wh[j * 256 + k] = (f16)(w * scp);
    red[k] = shp * w;
    __syncthreads();
    for (int s = 128; s > 0; s >>= 1) {
        if (k < s) red[k] += red[k + s];
        __syncthreads();
    }
    if (k == 0) bias2[j] = bl[j] + red[0];
}

// ================= fused scatter (fixed-capacity buckets) + cvt + gb =================
__global__ __launch_bounds__(256)
void scatcvt_kernel(const float* __restrict__ x, const int* __restrict__ src,
                    const int* __restrict__ dst, const int* __restrict__ batch,
                    int* __restrict__ bcur, unsigned* __restrict__ staging,
                    f16* __restrict__ hf, int* __restrict__ gb) {
    if (blockIdx.x < NCNT) {
        __shared__ int h[NB];
        __shared__ int rbase[NB];
        for (int i = threadIdx.x; i < NB; i += 256) h[i] = 0;
        __syncthreads();
        int base = blockIdx.x * EPB;
#pragma unroll
        for (int it = 0; it < EPB / 256; ++it) {
            int e = base + it * 256 + threadIdx.x;
            if (e < NE) atomicAdd(&h[dst[e] >> 8], 1);
        }
        __syncthreads();
        for (int i = threadIdx.x; i < NB; i += 256) {
            rbase[i] = h[i] ? atomicAdd(&bcur[i], h[i]) : 0;
            h[i] = 0;
        }
        __syncthreads();
#pragma unroll
        for (int it = 0; it < EPB / 256; ++it) {
            int e = base + it * 256 + threadIdx.x;
            if (e < NE) {
                int d = dst[e];
                int k = d >> 8;
                int p = rbase[k] + atomicAdd(&h[k], 1);
                if (p < CAP)  // capacity guard (statistically impossible to trip)
                    staging[(size_t)k * CAP + p] = ((unsigned)d << 16) | (unsigned)src[e];
            }
        }
    } else {
        int t = (blockIdx.x - NCNT) * 256 + threadIdx.x;  // t < NN*16 exactly
        if (t < NN) {
            int b = batch[t];
            int bp = (t == 0) ? -1 : batch[t - 1];
            for (int g = bp + 1; g <= b; ++g) gb[g] = t;
            if (t == NN - 1)
                for (int g = b + 1; g <= NG; ++g) gb[g] = NN;
        }
        int n = t >> 4, q = t & 15;
        float4 v0 = ((const float4*)x)[n * 32 + q * 2];
        float4 v1 = ((const float4*)x)[n * 32 + q * 2 + 1];
        f16x8 o;
        o[0] = (f16)v0.x; o[1] = (f16)v0.y; o[2] = (f16)v0.z; o[3] = (f16)v0.w;
        o[4] = (f16)v1.x; o[5] = (f16)v1.y; o[6] = (f16)v1.z; o[7] = (f16)v1.w;
        *(f16x8*)(hf + (size_t)n * HD + q * 8) = o;
    }
}

// ===== per-bucket build (blocks 0..NB-1) + layer-0 weight prep (blocks NB..NB+127) =====
__global__ __launch_bounds__(256)
void buckbuild_kernel(const unsigned* __restrict__ staging, const int* __restrict__ bcur,
                      int* __restrict__ rowinfo, int* __restrict__ perm,
                      const float* __restrict__ Wl0, const float* __restrict__ Wr0,
                      const float* __restrict__ bl0, f16* __restrict__ Wh,
                      float* __restrict__ bias2) {
    __shared__ __align__(16) char sm[2048 + 2 * CAP];
    const int tid = threadIdx.x;
    if (blockIdx.x >= NB) {  // layer-0 weight prep rides along (no stats dependency)
        wprep_body(blockIdx.x - NB, tid, (float*)sm, nullptr, nullptr, nullptr,
                   Wl0, Wr0, bl0, Wh, bias2);
        return;
    }
    int* cnt = (int*)sm;
    int* pre = cnt + 256;
    unsigned short* lperm = (unsigned short*)(pre + 256);
    const int k = blockIdx.x;
    const int base = k * CAP;
    int size = bcur[k];
    if (size > CAP) size = CAP;
    cnt[tid] = 0;
    __syncthreads();
    for (int i = tid; i < size; i += 256)
        atomicAdd(&cnt[(int)(staging[base + i] >> 16) - k * 256], 1);
    __syncthreads();
    int v = cnt[tid];
    pre[tid] = v;
    __syncthreads();
    for (int off = 1; off < 256; off <<= 1) {
        int t2 = (tid >= off) ? pre[tid - off] : 0;
        __syncthreads();
        pre[tid] += t2;
        __syncthreads();
    }
    int excl = pre[tid] - v;
    int n = k * 256 + tid;
    if (n < NN) rowinfo[n] = excl | (v << 16);
    cnt[tid] = excl;  // reuse as scatter cursors
    __syncthreads();
    for (int i = tid; i < size; i += 256) {
        unsigned w = staging[base + i];
        int dl = (int)(w >> 16) - k * 256;
        int p = atomicAdd(&cnt[dl], 1);
        lperm[p] = (unsigned short)(w & 0xffffu);  // src < 65536 (NN=50000)
    }
    __syncthreads();
    for (int i = tid; i < size; i += 256) perm[base + i] = (int)lperm[i];
}

// ================= standalone weight prep for layers 1,2 (needs prev stats) =================
__global__ __launch_bounds__(256)
void wprep_kernel(const float* __restrict__ statsPrev, const float* __restrict__ gamP,
                  const float* __restrict__ betP, const float* __restrict__ Wl,
                  const float* __restrict__ Wr, const float* __restrict__ bl,
                  f16* __restrict__ Wh, float* __restrict__ bias2) {
    __shared__ float red[256];
    wprep_body(blockIdx.x, threadIdx.x, red, statsPrev, gamP, betP, Wl, Wr, bl, Wh, bias2);
}

// ============ fused per-tile kernel: gather(->LDS) + MFMA + epilogue ============
// One block = 64 output rows. Gather aggregates into LDS (no aggf global
// round-trip). Last layer: output never materialized; per-block row-sums go
// straight into pooled replicas (BN affine folds past the sum; boundary blocks
// take an LDS split path). No inter-block sync of any kind.
__global__ __launch_bounds__(256, 4)
void fused_kernel(const f16* __restrict__ hin, const int* __restrict__ rowinfo,
                  const int* __restrict__ perm, const float* __restrict__ statsPrev,
                  const float* __restrict__ gamP, const float* __restrict__ betP,
                  const f16* __restrict__ Wh, const float* __restrict__ bias2,
                  f16* __restrict__ yout, float* __restrict__ statsN,
                  const int* __restrict__ batch, float* __restrict__ pooledR,
                  int lastl) {
    __shared__ __align__(16) char smraw[35840];  // wls 34816 + st 1024; alias alds/ls/pl
    const int tid = threadIdx.x;
    const int u = blockIdx.x;
    const int brow = u * 64;
    f16* alds = (f16*)smraw;                 // [64][ASTR] f16 aggregate tile (17408B)
    float* st = (float*)(smraw + 34816);     // [256] stats accumulators
    st[tid] = 0.0f;

    // ---- gather into LDS: 16 lanes/node (q each 8 ch, 256B contiguous/row), 4 reps ----
    {
        const int q = tid & 15;
        const f16* hq = hin + q * 8;
        for (int rep = 0; rep < 4; ++rep) {
            int i = rep * 16 + (tid >> 4);
            int n = brow + i;
            float s[8] = {0.f, 0.f, 0.f, 0.f, 0.f, 0.f, 0.f, 0.f};
            if (n < NN) {
                int ri = rowinfo[n];
                int dg = ri >> 16;
                int r0 = (n >> 8) * CAP + (ri & 0xffff);
                int r1 = r0 + dg;
                int e = r0;
                for (; e + 4 <= r1; e += 4) {
                    int i0 = perm[e], i1 = perm[e + 1], i2 = perm[e + 2], i3 = perm[e + 3];
                    f16x8 v0 = *(const f16x8*)(hq + (size_t)i0 * HD);
                    f16x8 v1 = *(const f16x8*)(hq + (size_t)i1 * HD);
                    f16x8 v2 = *(const f16x8*)(hq + (size_t)i2 * HD);
                    f16x8 v3 = *(const f16x8*)(hq + (size_t)i3 * HD);
#pragma unroll
                    for (int j = 0; j < 8; ++j)
                        s[j] += ((float)v0[j] + (float)v1[j]) + ((float)v2[j] + (float)v3[j]);
                }
                if (e + 2 <= r1) {
                    int i0 = perm[e], i1 = perm[e + 1];
                    f16x8 v0 = *(const f16x8*)(hq + (size_t)i0 * HD);
                    f16x8 v1 = *(const f16x8*)(hq + (size_t)i1 * HD);
#pragma unroll
                    for (int j = 0; j < 8; ++j) s[j] += (float)v0[j] + (float)v1[j];
                    e += 2;
                }
                if (e < r1) {
                    int i0 = perm[e];
                    f16x8 v0 = *(const f16x8*)(hq + (size_t)i0 * HD);
#pragma unroll
                    for (int j = 0; j < 8; ++j) s[j] += (float)v0[j];
                }
                if (dg > 0) {
                    float rr = 1.0f / (float)dg;
#pragma unroll
                    for (int j = 0; j < 8; ++j) s[j] *= rr;
                } else if (statsPrev) {
                    // deg-0 sentinel: -sh/sc so the BN-folded GEMM contribution is 0
                    for (int j = 0; j < 8; ++j) {
                        float sc, sh;
                        bn_affine(statsPrev, q * 8 + j, gamP, betP, &sc, &sh);
                        s[j] = (sc != 0.f) ? (-sh / sc) : 0.f;
                    }
                }
            }
            f16x8 o;
#pragma unroll
            for (int j = 0; j < 8; ++j) o[j] = (f16)s[j];
            *(f16x8*)&alds[i * ASTR + q * 8] = o;
        }
    }
    __syncthreads();

    // ---- A fragments: agg half from LDS, self half from global (contiguous) ----
    const int wave = tid >> 6, lane = tid & 63;
    const int lm = lane & 15, quad = lane >> 4;
    const int m0 = brow + wave * 16;
    f16x8 a[8];
#pragma unroll
    for (int c = 0; c < 4; ++c)
        a[c] = *(const f16x8*)&alds[(wave * 16 + lm) * ASTR + c * 32 + quad * 8];
    int ar = m0 + lm;
    if (ar >= NN) ar = NN - 1;
#pragma unroll
    for (int c = 0; c < 4; ++c)
        a[4 + c] = *(const f16x8*)(hin + (size_t)ar * HD + c * 32 + quad * 8);
    __syncthreads();  // alds dead; LDS reusable for wls

    // ---- MFMA: B staged in LDS ----
    f16* wls = (f16*)smraw;
    float* ls = (float*)smraw;
    f32x4 acc[8];
#pragma unroll
    for (int t = 0; t < 8; ++t) acc[t] = (f32x4){0.f, 0.f, 0.f, 0.f};
#pragma unroll
    for (int half = 0; half < 2; ++half) {
        __syncthreads();
#pragma unroll
        for (int it = 0; it < 8; ++it) {
            int slot = tid + it * 256;
            int r = slot >> 4, c = slot & 15;
            *(f16x8*)&wls[r * WSTR + c * 8] =
                *(const f16x8*)(Wh + (size_t)r * 256 + half * 128 + c * 8);
        }
        __syncthreads();
#pragma unroll
        for (int c = 0; c < 4; ++c) {
#pragma unroll
            for (int t = 0; t < 8; ++t) {
                f16x8 b = *(const f16x8*)&wls[(t * 16 + lm) * WSTR + c * 32 + quad * 8];
                acc[t] = __builtin_amdgcn_mfma_f32_16x16x32_f16(a[half * 4 + c], b, acc[t], 0, 0, 0);
            }
        }
    }
    __syncthreads();

    // ---- epilogue ----
    int gmin = 0, gmaxr = 0, boundary = 0;
    float* pl = (float*)smraw;  // [2][128] boundary-split pool (aliases dead wls)
    if (lastl) {
        gmin = batch[brow];
        int lastrow = brow + 63;
        if (lastrow >= NN) lastrow = NN - 1;
        gmaxr = batch[lastrow];
        boundary = (gmin != gmaxr);
        if (boundary) pl[tid] = 0.f;
    }
    __syncthreads();

#pragma unroll
    for (int t = 0; t < 8; ++t) {
        int n = t * 16 + lm;
        float bs = bias2[n];
        float s = 0.f, sq = 0.f;
#pragma unroll
        for (int r = 0; r < 4; ++r) {
            int gr = m0 + quad * 4 + r;
            float y = fmaxf(acc[t][r] + bs, 0.f);
            if (gr >= NN) y = 0.f;
            if (!lastl) ls[(wave * 16 + quad * 4 + r) * 132 + n] = y;
            else if (boundary && gr < NN) {
                int gi = batch[gr] - gmin;
                gi = gi < 0 ? 0 : (gi > 1 ? 1 : gi);
                atomicAdd(&pl[gi * 128 + n], y);
            }
            s += y; sq += y * y;
        }
        s += __shfl_xor(s, 16); s += __shfl_xor(s, 32);
        sq += __shfl_xor(sq, 16); sq += __shfl_xor(sq, 32);
        if (quad == 0) { atomicAdd(&st[n], s); atomicAdd(&st[128 + n], sq); }
    }
    __syncthreads();
    atomicAdd(&statsN[(u & (NREP - 1)) * 256 + tid], st[tid]);

    if (!lastl) {
#pragma unroll
        for (int it = 0; it < 4; ++it) {
            int slot = tid + it * 256;
            int r = slot >> 4, c = slot & 15;
            int g = brow + r;
            if (g < NN) {
                const float* p = &ls[r * 132 + c * 8];
                f16x8 o;
#pragma unroll
                for (int j = 0; j < 8; ++j) o[j] = (f16)p[j];
                *(f16x8*)(yout + (size_t)g * HD + c * 8) = o;
            }
        }
    } else {
        float* pr = pooledR + (size_t)(u & 7) * NG * HD;
        if (!boundary) {
            // st[c] == sum of this block's y over its 64 rows (single group)
            if (tid < HD) atomicAdd(&pr[gmin * HD + tid], st[tid]);
        } else {
            int gg = tid >> 7, c = tid & 127;
            int g = gmin + gg;
            if (g <= gmaxr && g < NG) atomicAdd(&pr[g * HD + c], pl[gg * 128 + c]);
        }
    }
}

// ---------------- head: layer-3 BN (replicated stats) + replica-summed pool + sigmoid ----
__global__ void head_kernel(const float* __restrict__ pooledR, const int* __restrict__ gb,
                            const float* __restrict__ stats3, const float* __restrict__ gam3,
                            const float* __restrict__ bet3, const float* __restrict__ fcw,
                            const float* __restrict__ fcb, float* __restrict__ out) {
    __shared__ float red[2];
    int g = blockIdx.x, c = threadIdx.x;  // 128 threads
    float sc, sh;
    bn_affine(stats3, c, gam3, bet3, &sc, &sh);
    float p = 0.f;
#pragma unroll
    for (int r = 0; r < 8; ++r) p += pooledR[(size_t)r * NG * HD + g * HD + c];
    float cnt = (float)(gb[g + 1] - gb[g]);
    float v = (p * sc + cnt * sh) * fcw[c];
#pragma unroll
    for (int o = 32; o > 0; o >>= 1) v += __shfl_xor(v, o);
    if ((c & 63) == 0) red[c >> 6] = v;
    __syncthreads();
    if (c == 0) {
        float s = red[0] + red[1] + fcb[0];
        out[g] = 1.0f / (1.0f + expf(-s));
    }
}

extern "C" void kernel_launch(void* const* d_in, const int* in_sizes, int n_in,
                              void* d_out, int out_size, void* d_ws, size_t ws_size,
                              hipStream_t stream) {
    const float* x     = (const float*)d_in[0];
    const int*   ei    = (const int*)d_in[1];
    const int*   src   = ei;
    const int*   dst   = ei + NE;
    const int*   batch = (const int*)d_in[3];
    const float* Wl    = (const float*)d_in[4];
    const float* bl    = (const float*)d_in[5];
    const float* Wr    = (const float*)d_in[6];
    const float* gamma = (const float*)d_in[7];
    const float* beta  = (const float*)d_in[8];
    const float* fcw   = (const float*)d_in[9];
    const float* fcb   = (const float*)d_in[10];
    float* out = (float*)d_out;

    f16* hf0  = (f16*)d_ws;                       // [NN][128] fp16 (x converted)
    f16* hfA  = hf0 + (size_t)NN * HD;
    f16* hfB  = hfA + (size_t)NN * HD;
    f16* Wh   = hfB + (size_t)NN * HD;            // [128][256] fp16
    float* bias2 = (float*)(Wh + 128 * 256);      // 128
    // ---- contiguous zero zone (single memset) ----
    float* zero0    = bias2 + HD;
    float* statsRaw = zero0;                      // 3 layers x NREP x 256
    float* pooledR  = statsRaw + 3 * NREP * 256;  // 8 replicas x NG x HD
    int* bcur  = (int*)(pooledR + 8 * NG * HD);   // NB relative cursors
    size_t zero_bytes = (3 * NREP * 256 + 8 * NG * HD) * sizeof(float) + NB * sizeof(int);
    // ---- rest ----
    int* rowinfo = bcur + NB;                     // NN
    int* gb      = rowinfo + NN;                  // NG+1
    int* perm    = gb + NG + 1;                   // NB*CAP (padded CSR)
    // staging ALIASES hfB: staging live window (scatcvt->buckbuild) ends before
    // hfB's first write (fused layer 1). Keeps total footprint ~45MB (R5-proven trick).
    unsigned* staging = (unsigned*)hfB;           // NB*CAP (6.42MB < 12.8MB)

    hipMemsetAsync(zero0, 0, zero_bytes, stream);

    scatcvt_kernel<<<NCNT + GATHB, 256, 0, stream>>>(x, src, dst, batch, bcur,
                                                     staging, hf0, gb);
    // per-bucket CSR build + layer-0 weight prep (no stats dep) in one launch
    buckbuild_kernel<<<NB + 128, 256, 0, stream>>>(staging, bcur, rowinfo, perm,
                                                   Wl, Wr, bl, Wh, bias2);

    const f16* hin = hf0;
    f16* houts[3] = {hfA, hfB, nullptr};
    for (int l = 0; l < NL; ++l) {
        const float* stP = (l == 0) ? nullptr : (statsRaw + (size_t)(l - 1) * NREP * 256);
        const float* gP  = gamma + (l == 0 ? 0 : (l - 1)) * HD;
        const float* bP  = beta + (l == 0 ? 0 : (l - 1)) * HD;
        if (l > 0)  // stream-ordered weight prep (stats from layer l-1 are complete)
            wprep_kernel<<<128, 256, 0, stream>>>(stP, gP, bP, Wl + (size_t)l * HD * HD,
                                                  Wr + (size_t)l * HD * HD, bl + l * HD,
                                                  Wh, bias2);
        fused_kernel<<<GEMMB, 256, 0, stream>>>(
            hin, rowinfo, perm, stP, gP, bP, Wh, bias2,
            houts[l], statsRaw + (size_t)l * NREP * 256, batch, pooledR,
            (l == NL - 1) ? 1 : 0);
        hin = houts[l];
    }
    head_kernel<<<NG, 128, 0, stream>>>(pooledR, gb, statsRaw + 2 * NREP * 256,
                                        gamma + 2 * HD, beta + 2 * HD, fcw, fcb, out);
}

// Round 8
// 292.112 us; speedup vs baseline: 1.0280x; 1.0280x over previous
//
#include <hip/hip_runtime.h>
#include <math.h>

#define NN 50000
#define NE 800000
#define HD 128
#define NL 3
#define NG 64
#define BN_EPS 1e-5f
#define NB 196   // dst buckets of 256 nodes
#define EPB 4096 // edges per block in bucket scatter
#define NCNT ((NE + EPB - 1) / EPB)     // 196 scatter blocks
#define CAP 8192 // fixed bucket capacity (mean 4096 + 64 sigma)
#define WSTR 136 // LDS weight row stride (fp16 elems)
#define NREP 32  // stats replicas (TCC same-address contention /32)
#define GATHB ((NN * 16) / 256)         // 3125 gather/cvt blocks (exact)

typedef _Float16 f16;
typedef __attribute__((ext_vector_type(8))) _Float16 f16x8;
typedef __attribute__((ext_vector_type(4))) float f32x4;

// ================= fused scatter (fixed-capacity buckets) + cvt + gb =================
__global__ __launch_bounds__(256)
void scatcvt_kernel(const float* __restrict__ x, const int* __restrict__ src,
                    const int* __restrict__ dst, const int* __restrict__ batch,
                    int* __restrict__ bcur, unsigned* __restrict__ staging,
                    f16* __restrict__ hf, int* __restrict__ gb) {
    if (blockIdx.x < NCNT) {
        __shared__ int h[NB];
        __shared__ int rbase[NB];
        for (int i = threadIdx.x; i < NB; i += 256) h[i] = 0;
        __syncthreads();
        int base = blockIdx.x * EPB;
#pragma unroll
        for (int it = 0; it < EPB / 256; ++it) {
            int e = base + it * 256 + threadIdx.x;
            if (e < NE) atomicAdd(&h[dst[e] >> 8], 1);
        }
        __syncthreads();
        for (int i = threadIdx.x; i < NB; i += 256) {
            rbase[i] = h[i] ? atomicAdd(&bcur[i], h[i]) : 0;
            h[i] = 0;
        }
        __syncthreads();
#pragma unroll
        for (int it = 0; it < EPB / 256; ++it) {
            int e = base + it * 256 + threadIdx.x;
            if (e < NE) {
                int d = dst[e];
                int k = d >> 8;
                int p = rbase[k] + atomicAdd(&h[k], 1);
                if (p < CAP)  // capacity guard (statistically impossible to trip)
                    staging[(size_t)k * CAP + p] = ((unsigned)d << 16) | (unsigned)src[e];
            }
        }
    } else {
        // ---- cvt block: fp32 -> fp16 row conversion + group-boundary table ----
        int t = (blockIdx.x - NCNT) * 256 + threadIdx.x;  // t < NN*16 exactly
        if (t < NN) {
            int b = batch[t];
            int bp = (t == 0) ? -1 : batch[t - 1];
            for (int g = bp + 1; g <= b; ++g) gb[g] = t;
            if (t == NN - 1)
                for (int g = b + 1; g <= NG; ++g) gb[g] = NN;
        }
        int n = t >> 4, q = t & 15;
        float4 v0 = ((const float4*)x)[n * 32 + q * 2];
        float4 v1 = ((const float4*)x)[n * 32 + q * 2 + 1];
        f16x8 o;
        o[0] = (f16)v0.x; o[1] = (f16)v0.y; o[2] = (f16)v0.z; o[3] = (f16)v0.w;
        o[4] = (f16)v1.x; o[5] = (f16)v1.y; o[6] = (f16)v1.z; o[7] = (f16)v1.w;
        *(f16x8*)(hf + (size_t)n * HD + q * 8) = o;
    }
}

// ================= per-bucket build: local counting sort -> rowinfo + perm =================
// rowinfo[n] = excl | (deg<<16); row start = (n>>8)*CAP + excl (padded CSR).
__global__ __launch_bounds__(256)
void buckbuild_kernel(const unsigned* __restrict__ staging, const int* __restrict__ bcur,
                      int* __restrict__ rowinfo, int* __restrict__ perm) {
    __shared__ int cnt[256];
    __shared__ int pre[256];
    __shared__ unsigned short lperm[CAP];
    const int k = blockIdx.x;
    const int base = k * CAP;
    int size = bcur[k];
    if (size > CAP) size = CAP;
    const int tid = threadIdx.x;
    cnt[tid] = 0;
    __syncthreads();
    for (int i = tid; i < size; i += 256)
        atomicAdd(&cnt[(int)(staging[base + i] >> 16) - k * 256], 1);
    __syncthreads();
    int v = cnt[tid];
    pre[tid] = v;
    __syncthreads();
    for (int off = 1; off < 256; off <<= 1) {
        int t2 = (tid >= off) ? pre[tid - off] : 0;
        __syncthreads();
        pre[tid] += t2;
        __syncthreads();
    }
    int excl = pre[tid] - v;
    int n = k * 256 + tid;
    if (n < NN) rowinfo[n] = excl | (v << 16);
    cnt[tid] = excl;  // reuse as scatter cursors
    __syncthreads();
    for (int i = tid; i < size; i += 256) {
        unsigned w = staging[base + i];
        int dl = (int)(w >> 16) - k * 256;
        int p = atomicAdd(&cnt[dl], 1);
        lperm[p] = (unsigned short)(w & 0xffffu);  // src < 65536 (NN=50000)
    }
    __syncthreads();
    for (int i = tid; i < size; i += 256) perm[base + i] = (int)lperm[i];
}

// BN affine from replicated raw sums
__device__ __forceinline__ void bn_affine(const float* __restrict__ sR, int c,
                                          const float* __restrict__ gam,
                                          const float* __restrict__ bet,
                                          float* sc, float* sh) {
    float s0 = 0.f, s1 = 0.f;
#pragma unroll 8
    for (int r = 0; r < NREP; ++r) {
        s0 += sR[r * 256 + c];
        s1 += sR[r * 256 + 128 + c];
    }
    float invN = 1.0f / (float)NN;
    float mu = s0 * invN;
    float var = s1 * invN - mu * mu;
    var = var < 0.f ? 0.f : var;
    float s = rsqrtf(var + BN_EPS) * gam[c];
    *sc = s;
    *sh = bet[c] - mu * s;
}

// ============ fused gather + weight-prep launch (R5-proven, max TLP) ============
__global__ __launch_bounds__(256, 8)
void gatherw_kernel(const f16* __restrict__ hf, const int* __restrict__ rowinfo,
                    const int* __restrict__ perm,
                    const float* __restrict__ statsPrev,  // null for layer 0
                    const float* __restrict__ gamP, const float* __restrict__ betP,
                    const float* __restrict__ Wl, const float* __restrict__ Wr,
                    const float* __restrict__ bl,
                    f16* __restrict__ Wh, float* __restrict__ bias2,
                    f16* __restrict__ aggf) {
    __shared__ float red[256];
    if (blockIdx.x >= GATHB) {
        int j = blockIdx.x - GATHB;   // output channel
        int k = threadIdx.x;          // contraction index
        float scp = 1.0f, shp = 0.0f;
        if (statsPrev) bn_affine(statsPrev, k & 127, gamP, betP, &scp, &shp);
        float w = (k < HD) ? Wl[j * HD + k] : Wr[j * HD + (k - HD)];
        Wh[j * 256 + k] = (f16)(w * scp);
        red[k] = shp * w;
        __syncthreads();
        for (int s = 128; s > 0; s >>= 1) {
            if (k < s) red[k] += red[k + s];
            __syncthreads();
        }
        if (k == 0) bias2[j] = bl[j] + red[0];
        return;
    }
    // ---- gather block ----
    int t = blockIdx.x * 256 + threadIdx.x;   // t < NN*16 exactly
    int n = t >> 4, q = t & 15;
    int ri = rowinfo[n];
    int dg = ri >> 16;
    int r0 = (n >> 8) * CAP + (ri & 0xffff);
    int r1 = r0 + dg;
    const f16* hq = hf + q * 8;   // channel-sliced base
    float s[8] = {0.f, 0.f, 0.f, 0.f, 0.f, 0.f, 0.f, 0.f};
    int e = r0;
    for (; e + 4 <= r1; e += 4) {
        int i0 = perm[e], i1 = perm[e + 1], i2 = perm[e + 2], i3 = perm[e + 3];
        f16x8 v0 = *(const f16x8*)(hq + (size_t)i0 * HD);
        f16x8 v1 = *(const f16x8*)(hq + (size_t)i1 * HD);
        f16x8 v2 = *(const f16x8*)(hq + (size_t)i2 * HD);
        f16x8 v3 = *(const f16x8*)(hq + (size_t)i3 * HD);
#pragma unroll
        for (int j = 0; j < 8; ++j)
            s[j] += ((float)v0[j] + (float)v1[j]) + ((float)v2[j] + (float)v3[j]);
    }
    if (e + 2 <= r1) {
        int i0 = perm[e], i1 = perm[e + 1];
        f16x8 v0 = *(const f16x8*)(hq + (size_t)i0 * HD);
        f16x8 v1 = *(const f16x8*)(hq + (size_t)i1 * HD);
#pragma unroll
        for (int j = 0; j < 8; ++j) s[j] += (float)v0[j] + (float)v1[j];
        e += 2;
    }
    if (e < r1) {
        int i0 = perm[e];
        f16x8 v0 = *(const f16x8*)(hq + (size_t)i0 * HD);
#pragma unroll
        for (int j = 0; j < 8; ++j) s[j] += (float)v0[j];
    }
    if (dg > 0) {
        float r = 1.0f / (float)dg;
#pragma unroll
        for (int j = 0; j < 8; ++j) s[j] *= r;
    } else if (statsPrev) {
        // deg-0 sentinel: -sh/sc so the BN-folded GEMM contribution is exactly 0
#pragma unroll
        for (int j = 0; j < 8; ++j) {
            float sc, sh;
            bn_affine(statsPrev, q * 8 + j, gamP, betP, &sc, &sh);
            s[j] = (sc != 0.f) ? (-sh / sc) : 0.f;
        }
    }  // layer 0: sentinel is 0 (identity affine), s[] already 0
    f16x8 o;
#pragma unroll
    for (int j = 0; j < 8; ++j) o[j] = (f16)s[j];
    *(f16x8*)(aggf + (size_t)n * HD + q * 8) = o;
}

// ------- fp16 MFMA GEMM, B staged in LDS, A hoisted, NREP stats; lastl pools in epilogue -------
__global__ __launch_bounds__(256, 4)
void mfma_gemm(const f16* __restrict__ aggf, const f16* __restrict__ hf,
               const f16* __restrict__ Wh, const float* __restrict__ bias2,
               f16* __restrict__ yout, float* __restrict__ statsN,
               const int* __restrict__ batch, float* __restrict__ pooledR,
               int lastl) {
    __shared__ f16 wls[128 * WSTR];   // 34816 B; aliased as f32 ls[64][132] / pl in epilogue
    __shared__ float st[256];
    float* ls = (float*)wls;
    const int tid = threadIdx.x;
    st[tid] = 0.0f;
    const int wave = tid >> 6, lane = tid & 63;
    const int lm = lane & 15, quad = lane >> 4;
    const int m0 = blockIdx.x * 64 + wave * 16;
    int ar = m0 + lm;
    if (ar >= NN) ar = NN - 1;

    f16x8 a[8];
#pragma unroll
    for (int c = 0; c < 4; ++c)
        a[c] = *(const f16x8*)(aggf + (size_t)ar * HD + c * 32 + quad * 8);
#pragma unroll
    for (int c = 0; c < 4; ++c)
        a[4 + c] = *(const f16x8*)(hf + (size_t)ar * HD + c * 32 + quad * 8);

    f32x4 acc[8];
#pragma unroll
    for (int t = 0; t < 8; ++t) acc[t] = (f32x4){0.f, 0.f, 0.f, 0.f};

#pragma unroll
    for (int half = 0; half < 2; ++half) {
        __syncthreads();
#pragma unroll
        for (int it = 0; it < 8; ++it) {
            int slot = tid + it * 256;
            int r = slot >> 4, c = slot & 15;
            *(f16x8*)&wls[r * WSTR + c * 8] =
                *(const f16x8*)(Wh + (size_t)r * 256 + half * 128 + c * 8);
        }
        __syncthreads();
#pragma unroll
        for (int c = 0; c < 4; ++c) {
#pragma unroll
            for (int t = 0; t < 8; ++t) {
                f16x8 b = *(const f16x8*)&wls[(t * 16 + lm) * WSTR + c * 32 + quad * 8];
                acc[t] = __builtin_amdgcn_mfma_f32_16x16x32_f16(a[half * 4 + c], b, acc[t], 0, 0, 0);
            }
        }
    }
    __syncthreads();

    // ---- epilogue (lastl: pool directly, never materialize yout) ----
    int gmin = 0, gmaxr = 0, boundary = 0;
    float* pl = (float*)wls;  // [2][128] boundary-split pool (aliases dead wls)
    if (lastl) {
        gmin = batch[m0 - wave * 16];  // == batch[blockIdx.x*64]
        int lastrow = blockIdx.x * 64 + 63;
        if (lastrow >= NN) lastrow = NN - 1;
        gmaxr = batch[lastrow];
        boundary = (gmin != gmaxr);
        if (boundary) pl[tid] = 0.f;
    }
    __syncthreads();

#pragma unroll
    for (int t = 0; t < 8; ++t) {
        int n = t * 16 + lm;
        float bs = bias2[n];
        float s = 0.f, sq = 0.f;
#pragma unroll
        for (int r = 0; r < 4; ++r) {
            int gr = m0 + quad * 4 + r;
            float y = fmaxf(acc[t][r] + bs, 0.f);
            if (gr >= NN) y = 0.f;
            if (!lastl) ls[(wave * 16 + quad * 4 + r) * 132 + n] = y;
            else if (boundary && gr < NN) {
                int gi = batch[gr] - gmin;
                gi = gi < 0 ? 0 : (gi > 1 ? 1 : gi);
                atomicAdd(&pl[gi * 128 + n], y);
            }
            s += y; sq += y * y;
        }
        s += __shfl_xor(s, 16); s += __shfl_xor(s, 32);
        sq += __shfl_xor(sq, 16); sq += __shfl_xor(sq, 32);
        if (quad == 0) { atomicAdd(&st[n], s); atomicAdd(&st[128 + n], sq); }
    }
    __syncthreads();
    atomicAdd(&statsN[(blockIdx.x & (NREP - 1)) * 256 + tid], st[tid]);

    if (!lastl) {
#pragma unroll
        for (int it = 0; it < 4; ++it) {
            int slot = tid + it * 256;
            int r = slot >> 4, c = slot & 15;
            int g = blockIdx.x * 64 + r;
            if (g < NN) {
                const float* p = &ls[r * 132 + c * 8];
                f16x8 o;
#pragma unroll
                for (int j = 0; j < 8; ++j) o[j] = (f16)p[j];
                *(f16x8*)(yout + (size_t)g * HD + c * 8) = o;
            }
        }
    } else {
        float* pr = pooledR + (size_t)(blockIdx.x & 7) * NG * HD;
        if (!boundary) {
            // st[c] == sum of this block's y over its 64 rows (single group)
            if (tid < HD) atomicAdd(&pr[gmin * HD + tid], st[tid]);
        } else {
            int gg = tid >> 7, c = tid & 127;
            int g = gmin + gg;
            if (g <= gmaxr && g < NG) atomicAdd(&pr[g * HD + c], pl[gg * 128 + c]);
        }
    }
}

// ---------------- head: layer-3 BN (replicated stats) + replica-summed pool + sigmoid ----
__global__ void head_kernel(const float* __restrict__ pooledR, const int* __restrict__ gb,
                            const float* __restrict__ stats3, const float* __restrict__ gam3,
                            const float* __restrict__ bet3, const float* __restrict__ fcw,
                            const float* __restrict__ fcb, float* __restrict__ out) {
    __shared__ float red[2];
    int g = blockIdx.x, c = threadIdx.x;  // 128 threads
    float sc, sh;
    bn_affine(stats3, c, gam3, bet3, &sc, &sh);
    float p = 0.f;
#pragma unroll
    for (int r = 0; r < 8; ++r) p += pooledR[(size_t)r * NG * HD + g * HD + c];
    float cnt = (float)(gb[g + 1] - gb[g]);
    float v = (p * sc + cnt * sh) * fcw[c];
#pragma unroll
    for (int o = 32; o > 0; o >>= 1) v += __shfl_xor(v, o);
    if ((c & 63) == 0) red[c >> 6] = v;
    __syncthreads();
    if (c == 0) {
        float s = red[0] + red[1] + fcb[0];
        out[g] = 1.0f / (1.0f + expf(-s));
    }
}

extern "C" void kernel_launch(void* const* d_in, const int* in_sizes, int n_in,
                              void* d_out, int out_size, void* d_ws, size_t ws_size,
                              hipStream_t stream) {
    const float* x     = (const float*)d_in[0];
    const int*   ei    = (const int*)d_in[1];
    const int*   src   = ei;
    const int*   dst   = ei + NE;
    const int*   batch = (const int*)d_in[3];
    const float* Wl    = (const float*)d_in[4];
    const float* bl    = (const float*)d_in[5];
    const float* Wr    = (const float*)d_in[6];
    const float* gamma = (const float*)d_in[7];
    const float* beta  = (const float*)d_in[8];
    const float* fcw   = (const float*)d_in[9];
    const float* fcb   = (const float*)d_in[10];
    float* out = (float*)d_out;

    f16* hf0  = (f16*)d_ws;                       // [NN][128] fp16 (x converted)
    f16* hfA  = hf0 + (size_t)NN * HD;
    f16* hfB  = hfA + (size_t)NN * HD;
    f16* aggf = hfB + (size_t)NN * HD;
    f16* Wh   = aggf + (size_t)NN * HD;           // [128][256] fp16
    float* bias2 = (float*)(Wh + 128 * 256);      // 128
    // ---- contiguous zero zone (single memset) ----
    float* zero0    = bias2 + HD;
    float* statsRaw = zero0;                      // 3 layers x NREP x 256
    float* pooledR  = statsRaw + 3 * NREP * 256;  // 8 replicas x NG x HD
    int* bcur  = (int*)(pooledR + 8 * NG * HD);   // NB relative cursors
    size_t zero_bytes = (3 * NREP * 256 + 8 * NG * HD) * sizeof(float) + NB * sizeof(int);
    // ---- rest ----
    int* rowinfo = bcur + NB;                     // NN
    int* gb      = rowinfo + NN;                  // NG+1
    int* perm    = gb + NG + 1;                   // NB*CAP (padded CSR)
    // staging ALIASES aggf: staging live window (scatcvt->buckbuild) ends before
    // aggf's first write (gatherw layer 0). R5-proven.
    unsigned* staging = (unsigned*)aggf;          // NB*CAP (6.42MB < 12.8MB)

    hipMemsetAsync(zero0, 0, zero_bytes, stream);

    scatcvt_kernel<<<NCNT + GATHB, 256, 0, stream>>>(x, src, dst, batch, bcur,
                                                     staging, hf0, gb);
    buckbuild_kernel<<<NB, 256, 0, stream>>>(staging, bcur, rowinfo, perm);

    const f16* hin = hf0;
    f16* houts[3] = {hfA, hfB, nullptr};
    for (int l = 0; l < NL; ++l) {
        const float* stP = (l == 0) ? nullptr : (statsRaw + (size_t)(l - 1) * NREP * 256);
        const float* gP  = gamma + (l == 0 ? 0 : (l - 1)) * HD;
        const float* bP  = beta + (l == 0 ? 0 : (l - 1)) * HD;
        gatherw_kernel<<<GATHB + 128, 256, 0, stream>>>(
            hin, rowinfo, perm, stP, gP, bP,
            Wl + (size_t)l * HD * HD, Wr + (size_t)l * HD * HD, bl + l * HD,
            Wh, bias2, aggf);
        mfma_gemm<<<(NN + 63) / 64, 256, 0, stream>>>(
            aggf, hin, Wh, bias2, houts[l], statsRaw + (size_t)l * NREP * 256,
            batch, pooledR, (l == NL - 1) ? 1 : 0);
        hin = houts[l];
    }
    head_kernel<<<NG, 128, 0, stream>>>(pooledR, gb, statsRaw + 2 * NREP * 256,
                                        gamma + 2 * HD, beta + 2 * HD, fcw, fcb, out);
}

// Round 9
// 282.782 us; speedup vs baseline: 1.0619x; 1.0330x over previous
//
#include <hip/hip_runtime.h>
#include <math.h>

#define NN 50000
#define NE 800000
#define HD 128
#define NL 3
#define NG 64
#define BN_EPS 1e-5f
#define NB 196   // dst buckets of 256 nodes
#define EPB 4096 // edges per block in bucket scatter
#define NCNT ((NE + EPB - 1) / EPB)     // 196 scatter blocks
#define CAP 8192 // fixed bucket capacity (mean 4096 + 64 sigma)
#define WSTR 136 // LDS weight row stride (fp16 elems)
#define NREP 32  // stats replicas (TCC same-address contention /32)
#define GATHB ((NN * 16) / 256)         // 3125 gather/cvt blocks (exact)

typedef _Float16 f16;
typedef __attribute__((ext_vector_type(8))) _Float16 f16x8;
typedef __attribute__((ext_vector_type(4))) float f32x4;

// ================= fused scatter (fixed-capacity buckets) + cvt + gb =================
__global__ __launch_bounds__(256)
void scatcvt_kernel(const float* __restrict__ x, const int* __restrict__ src,
                    const int* __restrict__ dst, const int* __restrict__ batch,
                    int* __restrict__ bcur, unsigned* __restrict__ staging,
                    f16* __restrict__ hf, int* __restrict__ gb) {
    if (blockIdx.x < NCNT) {
        __shared__ int h[NB];
        __shared__ int rbase[NB];
        for (int i = threadIdx.x; i < NB; i += 256) h[i] = 0;
        __syncthreads();
        int base = blockIdx.x * EPB;
#pragma unroll
        for (int it = 0; it < EPB / 256; ++it) {
            int e = base + it * 256 + threadIdx.x;
            if (e < NE) atomicAdd(&h[dst[e] >> 8], 1);
        }
        __syncthreads();
        for (int i = threadIdx.x; i < NB; i += 256) {
            rbase[i] = h[i] ? atomicAdd(&bcur[i], h[i]) : 0;
            h[i] = 0;
        }
        __syncthreads();
#pragma unroll
        for (int it = 0; it < EPB / 256; ++it) {
            int e = base + it * 256 + threadIdx.x;
            if (e < NE) {
                int d = dst[e];
                int k = d >> 8;
                int p = rbase[k] + atomicAdd(&h[k], 1);
                if (p < CAP)  // capacity guard (statistically impossible to trip)
                    staging[(size_t)k * CAP + p] = ((unsigned)d << 16) | (unsigned)src[e];
            }
        }
    } else {
        // ---- cvt block: fp32 -> fp16 row conversion + group-boundary table ----
        int t = (blockIdx.x - NCNT) * 256 + threadIdx.x;  // t < NN*16 exactly
        if (t < NN) {
            int b = batch[t];
            int bp = (t == 0) ? -1 : batch[t - 1];
            for (int g = bp + 1; g <= b; ++g) gb[g] = t;
            if (t == NN - 1)
                for (int g = b + 1; g <= NG; ++g) gb[g] = NN;
        }
        int n = t >> 4, q = t & 15;
        float4 v0 = ((const float4*)x)[n * 32 + q * 2];
        float4 v1 = ((const float4*)x)[n * 32 + q * 2 + 1];
        f16x8 o;
        o[0] = (f16)v0.x; o[1] = (f16)v0.y; o[2] = (f16)v0.z; o[3] = (f16)v0.w;
        o[4] = (f16)v1.x; o[5] = (f16)v1.y; o[6] = (f16)v1.z; o[7] = (f16)v1.w;
        *(f16x8*)(hf + (size_t)n * HD + q * 8) = o;
    }
}

// ================= per-bucket build: local counting sort -> rowinfo + perm =================
// rowinfo[n] = excl | (deg<<16); row start = (n>>8)*CAP + excl (padded CSR).
__global__ __launch_bounds__(256)
void buckbuild_kernel(const unsigned* __restrict__ staging, const int* __restrict__ bcur,
                      int* __restrict__ rowinfo, int* __restrict__ perm) {
    __shared__ int cnt[256];
    __shared__ int pre[256];
    __shared__ unsigned short lperm[CAP];
    const int k = blockIdx.x;
    const int base = k * CAP;
    int size = bcur[k];
    if (size > CAP) size = CAP;
    const int tid = threadIdx.x;
    cnt[tid] = 0;
    __syncthreads();
    for (int i = tid; i < size; i += 256)
        atomicAdd(&cnt[(int)(staging[base + i] >> 16) - k * 256], 1);
    __syncthreads();
    int v = cnt[tid];
    pre[tid] = v;
    __syncthreads();
    for (int off = 1; off < 256; off <<= 1) {
        int t2 = (tid >= off) ? pre[tid - off] : 0;
        __syncthreads();
        pre[tid] += t2;
        __syncthreads();
    }
    int excl = pre[tid] - v;
    int n = k * 256 + tid;
    if (n < NN) rowinfo[n] = excl | (v << 16);
    cnt[tid] = excl;  // reuse as scatter cursors
    __syncthreads();
    for (int i = tid; i < size; i += 256) {
        unsigned w = staging[base + i];
        int dl = (int)(w >> 16) - k * 256;
        int p = atomicAdd(&cnt[dl], 1);
        lperm[p] = (unsigned short)(w & 0xffffu);  // src < 65536 (NN=50000)
    }
    __syncthreads();
    for (int i = tid; i < size; i += 256) perm[base + i] = (int)lperm[i];
}

// BN affine from replicated raw sums
__device__ __forceinline__ void bn_affine(const float* __restrict__ sR, int c,
                                          const float* __restrict__ gam,
                                          const float* __restrict__ bet,
                                          float* sc, float* sh) {
    float s0 = 0.f, s1 = 0.f;
#pragma unroll 8
    for (int r = 0; r < NREP; ++r) {
        s0 += sR[r * 256 + c];
        s1 += sR[r * 256 + 128 + c];
    }
    float invN = 1.0f / (float)NN;
    float mu = s0 * invN;
    float var = s1 * invN - mu * mu;
    var = var < 0.f ? 0.f : var;
    float s = rsqrtf(var + BN_EPS) * gam[c];
    *sc = s;
    *sh = bet[c] - mu * s;
}

// ============ fused gather + weight-prep launch (R5-proven, max TLP) ============
__global__ __launch_bounds__(256, 8)
void gatherw_kernel(const f16* __restrict__ hf, const int* __restrict__ rowinfo,
                    const int* __restrict__ perm,
                    const float* __restrict__ statsPrev,  // null for layer 0
                    const float* __restrict__ gamP, const float* __restrict__ betP,
                    const float* __restrict__ Wl, const float* __restrict__ Wr,
                    const float* __restrict__ bl,
                    f16* __restrict__ Wh, float* __restrict__ bias2,
                    f16* __restrict__ aggf) {
    __shared__ float red[256];
    if (blockIdx.x >= GATHB) {
        int j = blockIdx.x - GATHB;   // output channel
        int k = threadIdx.x;          // contraction index
        float scp = 1.0f, shp = 0.0f;
        if (statsPrev) bn_affine(statsPrev, k & 127, gamP, betP, &scp, &shp);
        float w = (k < HD) ? Wl[j * HD + k] : Wr[j * HD + (k - HD)];
        Wh[j * 256 + k] = (f16)(w * scp);
        red[k] = shp * w;
        __syncthreads();
        for (int s = 128; s > 0; s >>= 1) {
            if (k < s) red[k] += red[k + s];
            __syncthreads();
        }
        if (k == 0) bias2[j] = bl[j] + red[0];
        return;
    }
    // ---- gather block ----
    int t = blockIdx.x * 256 + threadIdx.x;   // t < NN*16 exactly
    int n = t >> 4, q = t & 15;
    int ri = rowinfo[n];
    int dg = ri >> 16;
    int r0 = (n >> 8) * CAP + (ri & 0xffff);
    int r1 = r0 + dg;
    const f16* hq = hf + q * 8;   // channel-sliced base
    float s[8] = {0.f, 0.f, 0.f, 0.f, 0.f, 0.f, 0.f, 0.f};
    int e = r0;
    for (; e + 4 <= r1; e += 4) {
        int i0 = perm[e], i1 = perm[e + 1], i2 = perm[e + 2], i3 = perm[e + 3];
        f16x8 v0 = *(const f16x8*)(hq + (size_t)i0 * HD);
        f16x8 v1 = *(const f16x8*)(hq + (size_t)i1 * HD);
        f16x8 v2 = *(const f16x8*)(hq + (size_t)i2 * HD);
        f16x8 v3 = *(const f16x8*)(hq + (size_t)i3 * HD);
#pragma unroll
        for (int j = 0; j < 8; ++j)
            s[j] += ((float)v0[j] + (float)v1[j]) + ((float)v2[j] + (float)v3[j]);
    }
    if (e + 2 <= r1) {
        int i0 = perm[e], i1 = perm[e + 1];
        f16x8 v0 = *(const f16x8*)(hq + (size_t)i0 * HD);
        f16x8 v1 = *(const f16x8*)(hq + (size_t)i1 * HD);
#pragma unroll
        for (int j = 0; j < 8; ++j) s[j] += (float)v0[j] + (float)v1[j];
        e += 2;
    }
    if (e < r1) {
        int i0 = perm[e];
        f16x8 v0 = *(const f16x8*)(hq + (size_t)i0 * HD);
#pragma unroll
        for (int j = 0; j < 8; ++j) s[j] += (float)v0[j];
    }
    if (dg > 0) {
        float r = 1.0f / (float)dg;
#pragma unroll
        for (int j = 0; j < 8; ++j) s[j] *= r;
    } else if (statsPrev) {
        // deg-0 sentinel: -sh/sc so the BN-folded GEMM contribution is exactly 0
#pragma unroll
        for (int j = 0; j < 8; ++j) {
            float sc, sh;
            bn_affine(statsPrev, q * 8 + j, gamP, betP, &sc, &sh);
            s[j] = (sc != 0.f) ? (-sh / sc) : 0.f;
        }
    }  // layer 0: sentinel is 0 (identity affine), s[] already 0
    f16x8 o;
#pragma unroll
    for (int j = 0; j < 8; ++j) o[j] = (f16)s[j];
    *(f16x8*)(aggf + (size_t)n * HD + q * 8) = o;
}

// ------- fp16 MFMA GEMM, occupancy-restructured: N split in 2 halves, Wh staged in -------
// 16KB quarters. LDS 18432 B -> 8 blocks/CU co-resident (was 4 at 35840 B). acc[4]/wave.
__global__ __launch_bounds__(256, 4)
void mfma_gemm(const f16* __restrict__ aggf, const f16* __restrict__ hf,
               const f16* __restrict__ Wh, const float* __restrict__ bias2,
               f16* __restrict__ yout, float* __restrict__ statsN) {
    __shared__ f16 wls[64 * WSTR];    // 17408 B; aliased as f32 ls[64][68] in epilogue
    __shared__ float st[256];         // 1024 B
    float* ls = (float*)wls;
    const int tid = threadIdx.x;
    st[tid] = 0.0f;
    const int wave = tid >> 6, lane = tid & 63;
    const int lm = lane & 15, quad = lane >> 4;
    const int m0 = blockIdx.x * 64 + wave * 16;
    int ar = m0 + lm;
    if (ar >= NN) ar = NN - 1;

    // A fragments: K = [aggf 0..127 | hf 128..255]
    f16x8 a[8];
#pragma unroll
    for (int c = 0; c < 4; ++c)
        a[c] = *(const f16x8*)(aggf + (size_t)ar * HD + c * 32 + quad * 8);
#pragma unroll
    for (int c = 0; c < 4; ++c)
        a[4 + c] = *(const f16x8*)(hf + (size_t)ar * HD + c * 32 + quad * 8);

#pragma unroll
    for (int nh = 0; nh < 2; ++nh) {  // output-channel half
        f32x4 acc[4];
#pragma unroll
        for (int t = 0; t < 4; ++t) acc[t] = (f32x4){0.f, 0.f, 0.f, 0.f};
#pragma unroll
        for (int kh = 0; kh < 2; ++kh) {  // contraction half
            __syncthreads();
            // stage Wh[nh*64..+64)[kh*128..+128) -> wls[64][128]
#pragma unroll
            for (int it = 0; it < 4; ++it) {
                int slot = tid + it * 256;
                int r = slot >> 4, c = slot & 15;
                *(f16x8*)&wls[r * WSTR + c * 8] =
                    *(const f16x8*)(Wh + (size_t)(nh * 64 + r) * 256 + kh * 128 + c * 8);
            }
            __syncthreads();
#pragma unroll
            for (int c = 0; c < 4; ++c) {
#pragma unroll
                for (int t = 0; t < 4; ++t) {
                    f16x8 b = *(const f16x8*)&wls[(t * 16 + lm) * WSTR + c * 32 + quad * 8];
                    acc[t] = __builtin_amdgcn_mfma_f32_16x16x32_f16(a[kh * 4 + c], b, acc[t], 0, 0, 0);
                }
            }
        }
        __syncthreads();  // wls reads done; ls writes next (alias)

        // ---- epilogue for channels nh*64 .. nh*64+63 ----
#pragma unroll
        for (int t = 0; t < 4; ++t) {
            int n = nh * 64 + t * 16 + lm;
            float bs = bias2[n];
            float s = 0.f, sq = 0.f;
#pragma unroll
            for (int r = 0; r < 4; ++r) {
                int gr = m0 + quad * 4 + r;
                float y = fmaxf(acc[t][r] + bs, 0.f);
                if (gr >= NN) y = 0.f;
                ls[(wave * 16 + quad * 4 + r) * 68 + t * 16 + lm] = y;
                s += y; sq += y * y;
            }
            s += __shfl_xor(s, 16); s += __shfl_xor(s, 32);
            sq += __shfl_xor(sq, 16); sq += __shfl_xor(sq, 32);
            if (quad == 0) { atomicAdd(&st[n], s); atomicAdd(&st[128 + n], sq); }
        }
        __syncthreads();
        // store yout columns nh*64 .. +63 (128 B contiguous per row-half)
#pragma unroll
        for (int it = 0; it < 2; ++it) {
            int slot = tid + it * 256;
            int r = slot >> 3, cc = slot & 7;
            int g = blockIdx.x * 64 + r;
            if (g < NN) {
                const float* p = &ls[r * 68 + cc * 8];
                f16x8 o;
#pragma unroll
                for (int j = 0; j < 8; ++j) o[j] = (f16)p[j];
                *(f16x8*)(yout + (size_t)g * HD + nh * 64 + cc * 8) = o;
            }
        }
    }
    __syncthreads();
    atomicAdd(&statsN[(blockIdx.x & (NREP - 1)) * 256 + tid], st[tid]);
}

// ---------------- pooling: 8 splits/group (512 blocks; keeps CUs saturated) ----------
__global__ __launch_bounds__(256)
void pool2_kernel(const f16* __restrict__ hf, const int* __restrict__ gb,
                  float* __restrict__ pooled) {
    __shared__ float red[16 * 128];
    int g = blockIdx.x >> 3, sp = blockIdx.x & 7;
    int s = gb[g], e = gb[g + 1];
    int q = threadIdx.x & 15, r = threadIdx.x >> 4;
    float a[8] = {0.f, 0.f, 0.f, 0.f, 0.f, 0.f, 0.f, 0.f};
    for (int n = s + sp * 16 + r; n < e; n += 128) {
        f16x8 v = *(const f16x8*)(hf + (size_t)n * HD + q * 8);
#pragma unroll
        for (int j = 0; j < 8; ++j) a[j] += (float)v[j];
    }
#pragma unroll
    for (int j = 0; j < 8; ++j) red[r * 128 + q * 8 + j] = a[j];
    __syncthreads();
    for (int stp = 8; stp >= 1; stp >>= 1) {
        if (r < stp) {
#pragma unroll
            for (int j = 0; j < 8; ++j)
                red[r * 128 + q * 8 + j] += red[(r + stp) * 128 + q * 8 + j];
        }
        __syncthreads();
    }
    if (r == 0) {
#pragma unroll
        for (int j = 0; j < 8; ++j) atomicAdd(&pooled[g * HD + q * 8 + j], red[q * 8 + j]);
    }
}

// ---------------- head: layer-3 BN (from replicated stats) + dot + sigmoid ----------
__global__ void head_kernel(const float* __restrict__ pooled, const int* __restrict__ gb,
                            const float* __restrict__ stats3, const float* __restrict__ gam3,
                            const float* __restrict__ bet3, const float* __restrict__ fcw,
                            const float* __restrict__ fcb, float* __restrict__ out) {
    __shared__ float red[2];
    int g = blockIdx.x, c = threadIdx.x;  // 128 threads
    float sc, sh;
    bn_affine(stats3, c, gam3, bet3, &sc, &sh);
    float cnt = (float)(gb[g + 1] - gb[g]);
    float v = (pooled[g * HD + c] * sc + cnt * sh) * fcw[c];
#pragma unroll
    for (int o = 32; o > 0; o >>= 1) v += __shfl_xor(v, o);
    if ((c & 63) == 0) red[c >> 6] = v;
    __syncthreads();
    if (c == 0) {
        float s = red[0] + red[1] + fcb[0];
        out[g] = 1.0f / (1.0f + expf(-s));
    }
}

extern "C" void kernel_launch(void* const* d_in, const int* in_sizes, int n_in,
                              void* d_out, int out_size, void* d_ws, size_t ws_size,
                              hipStream_t stream) {
    const float* x     = (const float*)d_in[0];
    const int*   ei    = (const int*)d_in[1];
    const int*   src   = ei;
    const int*   dst   = ei + NE;
    const int*   batch = (const int*)d_in[3];
    const float* Wl    = (const float*)d_in[4];
    const float* bl    = (const float*)d_in[5];
    const float* Wr    = (const float*)d_in[6];
    const float* gamma = (const float*)d_in[7];
    const float* beta  = (const float*)d_in[8];
    const float* fcw   = (const float*)d_in[9];
    const float* fcb   = (const float*)d_in[10];
    float* out = (float*)d_out;

    f16* hf0  = (f16*)d_ws;                       // [NN][128] fp16 (x converted)
    f16* hfA  = hf0 + (size_t)NN * HD;
    f16* hfB  = hfA + (size_t)NN * HD;
    f16* aggf = hfB + (size_t)NN * HD;
    f16* Wh   = aggf + (size_t)NN * HD;           // [128][256] fp16
    float* bias2 = (float*)(Wh + 128 * 256);      // 128
    // ---- contiguous zero zone (single memset) ----
    float* zero0    = bias2 + HD;
    float* statsRaw = zero0;                      // 3 layers x NREP x 256
    float* pooled   = statsRaw + 3 * NREP * 256;  // NG*HD
    int* bcur  = (int*)(pooled + NG * HD);        // NB relative cursors
    size_t zero_bytes = (3 * NREP * 256 + NG * HD) * sizeof(float) + NB * sizeof(int);
    // ---- rest ----
    int* rowinfo = bcur + NB;                     // NN
    int* gb      = rowinfo + NN;                  // NG+1
    int* perm    = gb + NG + 1;                   // NB*CAP (padded CSR)
    // staging ALIASES aggf: staging live window (scatcvt->buckbuild) ends before
    // aggf's first write (gatherw layer 0). R5-proven.
    unsigned* staging = (unsigned*)aggf;          // NB*CAP (6.42MB < 12.8MB)

    hipMemsetAsync(zero0, 0, zero_bytes, stream);

    scatcvt_kernel<<<NCNT + GATHB, 256, 0, stream>>>(x, src, dst, batch, bcur,
                                                     staging, hf0, gb);
    buckbuild_kernel<<<NB, 256, 0, stream>>>(staging, bcur, rowinfo, perm);

    const f16* hin = hf0;
    f16* houts[3] = {hfA, hfB, hfA};
    for (int l = 0; l < NL; ++l) {
        const float* stP = (l == 0) ? nullptr : (statsRaw + (size_t)(l - 1) * NREP * 256);
        const float* gP  = gamma + (l == 0 ? 0 : (l - 1)) * HD;
        const float* bP  = beta + (l == 0 ? 0 : (l - 1)) * HD;
        gatherw_kernel<<<GATHB + 128, 256, 0, stream>>>(
            hin, rowinfo, perm, stP, gP, bP,
            Wl + (size_t)l * HD * HD, Wr + (size_t)l * HD * HD, bl + l * HD,
            Wh, bias2, aggf);
        mfma_gemm<<<(NN + 63) / 64, 256, 0, stream>>>(
            aggf, hin, Wh, bias2, houts[l], statsRaw + (size_t)l * NREP * 256);
        hin = houts[l];
    }
    pool2_kernel<<<NG * 8, 256, 0, stream>>>(hfA, gb, pooled);
    head_kernel<<<NG, 128, 0, stream>>>(pooled, gb, statsRaw + 2 * NREP * 256,
                                        gamma + 2 * HD, beta + 2 * HD, fcw, fcb, out);
}

// Round 10
// 269.702 us; speedup vs baseline: 1.1134x; 1.0485x over previous
//
#include <hip/hip_runtime.h>
#include <math.h>

#define NN 50000
#define NE 800000
#define HD 128
#define NL 3
#define NG 64
#define BN_EPS 1e-5f
#define NB 196   // dst buckets of 256 nodes
#define EPB 4096 // edges per block in bucket scatter
#define NCNT ((NE + EPB - 1) / EPB)     // 196 scatter blocks
#define CAP 8192 // fixed bucket capacity (mean 4096 + 64 sigma)
#define NREP 32  // stats replicas (TCC same-address contention /32)
#define GATHB ((NN * 16) / 256)         // 3125 cvt blocks (exact)
#define FUSEB (NN / 16)                 // 3125 fused tiles (NN = 16*3125 exactly)

typedef _Float16 f16;
typedef __attribute__((ext_vector_type(8))) _Float16 f16x8;
typedef __attribute__((ext_vector_type(4))) float f32x4;

// BN affine from replicated raw sums
__device__ __forceinline__ void bn_affine(const float* __restrict__ sR, int c,
                                          const float* __restrict__ gam,
                                          const float* __restrict__ bet,
                                          float* sc, float* sh) {
    float s0 = 0.f, s1 = 0.f;
#pragma unroll 8
    for (int r = 0; r < NREP; ++r) {
        s0 += sR[r * 256 + c];
        s1 += sR[r * 256 + 128 + c];
    }
    float invN = 1.0f / (float)NN;
    float mu = s0 * invN;
    float var = s1 * invN - mu * mu;
    var = var < 0.f ? 0.f : var;
    float s = rsqrtf(var + BN_EPS) * gam[c];
    *sc = s;
    *sh = bet[c] - mu * s;
}

// weight prep body: BN-folded Wh (fp16) + folded bias2. One block per output ch j.
__device__ __forceinline__ void wprep_body(int j, int k, float* red,
                                           const float* __restrict__ statsPrev,
                                           const float* __restrict__ gamP,
                                           const float* __restrict__ betP,
                                           const float* __restrict__ Wl,
                                           const float* __restrict__ Wr,
                                           const float* __restrict__ bl,
                                           f16* __restrict__ Wh,
                                           float* __restrict__ bias2) {
    float scp = 1.0f, shp = 0.0f;
    if (statsPrev) bn_affine(statsPrev, k & 127, gamP, betP, &scp, &shp);
    float w = (k < HD) ? Wl[j * HD + k] : Wr[j * HD + (k - HD)];
    Wh[j * 256 + k] = (f16)(w * scp);
    red[k] = shp * w;
    __syncthreads();
    for (int s = 128; s > 0; s >>= 1) {
        if (k < s) red[k] += red[k + s];
        __syncthreads();
    }
    if (k == 0) bias2[j] = bl[j] + red[0];
}

// ================= fused scatter (fixed-capacity buckets) + cvt + gb =================
__global__ __launch_bounds__(256)
void scatcvt_kernel(const float* __restrict__ x, const int* __restrict__ src,
                    const int* __restrict__ dst, const int* __restrict__ batch,
                    int* __restrict__ bcur, unsigned* __restrict__ staging,
                    f16* __restrict__ hf, int* __restrict__ gb) {
    if (blockIdx.x < NCNT) {
        __shared__ int h[NB];
        __shared__ int rbase[NB];
        for (int i = threadIdx.x; i < NB; i += 256) h[i] = 0;
        __syncthreads();
        int base = blockIdx.x * EPB;
#pragma unroll
        for (int it = 0; it < EPB / 256; ++it) {
            int e = base + it * 256 + threadIdx.x;
            if (e < NE) atomicAdd(&h[dst[e] >> 8], 1);
        }
        __syncthreads();
        for (int i = threadIdx.x; i < NB; i += 256) {
            rbase[i] = h[i] ? atomicAdd(&bcur[i], h[i]) : 0;
            h[i] = 0;
        }
        __syncthreads();
#pragma unroll
        for (int it = 0; it < EPB / 256; ++it) {
            int e = base + it * 256 + threadIdx.x;
            if (e < NE) {
                int d = dst[e];
                int k = d >> 8;
                int p = rbase[k] + atomicAdd(&h[k], 1);
                if (p < CAP)  // capacity guard (statistically impossible to trip)
                    staging[(size_t)k * CAP + p] = ((unsigned)d << 16) | (unsigned)src[e];
            }
        }
    } else {
        // ---- cvt block: fp32 -> fp16 row conversion + group-boundary table ----
        int t = (blockIdx.x - NCNT) * 256 + threadIdx.x;  // t < NN*16 exactly
        if (t < NN) {
            int b = batch[t];
            int bp = (t == 0) ? -1 : batch[t - 1];
            for (int g = bp + 1; g <= b; ++g) gb[g] = t;
            if (t == NN - 1)
                for (int g = b + 1; g <= NG; ++g) gb[g] = NN;
        }
        int n = t >> 4, q = t & 15;
        float4 v0 = ((const float4*)x)[n * 32 + q * 2];
        float4 v1 = ((const float4*)x)[n * 32 + q * 2 + 1];
        f16x8 o;
        o[0] = (f16)v0.x; o[1] = (f16)v0.y; o[2] = (f16)v0.z; o[3] = (f16)v0.w;
        o[4] = (f16)v1.x; o[5] = (f16)v1.y; o[6] = (f16)v1.z; o[7] = (f16)v1.w;
        *(f16x8*)(hf + (size_t)n * HD + q * 8) = o;
    }
}

// ===== per-bucket build (blocks 0..NB-1) + layer-0 weight prep (blocks NB..NB+127) =====
__global__ __launch_bounds__(256)
void buckbuild_kernel(const unsigned* __restrict__ staging, const int* __restrict__ bcur,
                      int* __restrict__ rowinfo, int* __restrict__ perm,
                      const float* __restrict__ Wl0, const float* __restrict__ Wr0,
                      const float* __restrict__ bl0, f16* __restrict__ Wh,
                      float* __restrict__ bias2) {
    __shared__ __align__(16) char sm[2048 + 2 * CAP];
    const int tid = threadIdx.x;
    if (blockIdx.x >= NB) {  // layer-0 weight prep rides along (no stats dependency)
        wprep_body(blockIdx.x - NB, tid, (float*)sm, nullptr, nullptr, nullptr,
                   Wl0, Wr0, bl0, Wh, bias2);
        return;
    }
    int* cnt = (int*)sm;
    int* pre = cnt + 256;
    unsigned short* lperm = (unsigned short*)(pre + 256);
    const int k = blockIdx.x;
    const int base = k * CAP;
    int size = bcur[k];
    if (size > CAP) size = CAP;
    cnt[tid] = 0;
    __syncthreads();
    for (int i = tid; i < size; i += 256)
        atomicAdd(&cnt[(int)(staging[base + i] >> 16) - k * 256], 1);
    __syncthreads();
    int v = cnt[tid];
    pre[tid] = v;
    __syncthreads();
    for (int off = 1; off < 256; off <<= 1) {
        int t2 = (tid >= off) ? pre[tid - off] : 0;
        __syncthreads();
        pre[tid] += t2;
        __syncthreads();
    }
    int excl = pre[tid] - v;
    int n = k * 256 + tid;
    if (n < NN) rowinfo[n] = excl | (v << 16);
    cnt[tid] = excl;  // reuse as scatter cursors
    __syncthreads();
    for (int i = tid; i < size; i += 256) {
        unsigned w = staging[base + i];
        int dl = (int)(w >> 16) - k * 256;
        int p = atomicAdd(&cnt[dl], 1);
        lperm[p] = (unsigned short)(w & 0xffffu);  // src < 65536 (NN=50000)
    }
    __syncthreads();
    for (int i = tid; i < size; i += 256) perm[base + i] = (int)lperm[i];
}

// ================= standalone weight prep for layers 1,2 (needs prev stats) =================
__global__ __launch_bounds__(256)
void wprep_kernel(const float* __restrict__ statsPrev, const float* __restrict__ gamP,
                  const float* __restrict__ betP, const float* __restrict__ Wl,
                  const float* __restrict__ Wr, const float* __restrict__ bl,
                  f16* __restrict__ Wh, float* __restrict__ bias2) {
    __shared__ float red[256];
    wprep_body(blockIdx.x, threadIdx.x, red, statsPrev, gamP, betP, Wl, Wr, bl, Wh, bias2);
}

// ===== fused16: gather 16 nodes (proven 16-lane/node pattern) -> M=16 MFMA GEMM =====
// 3125 blocks (= split-gather grid). LDS 22784B -> 7 blocks/CU; GEMM (no fabric
// traffic) hides inside the fabric-bound gather of co-resident blocks. No aggf.
__global__ __launch_bounds__(256, 7)
void fused16_kernel(const f16* __restrict__ hin, const int* __restrict__ rowinfo,
                    const int* __restrict__ perm, const float* __restrict__ statsPrev,
                    const float* __restrict__ gamP, const float* __restrict__ betP,
                    const f16* __restrict__ Wh, const float* __restrict__ bias2,
                    f16* __restrict__ yout, float* __restrict__ statsN) {
    __shared__ __align__(16) f16 alds[16 * 136];  // 4352 B agg tile (stride 136 f16)
    __shared__ __align__(16) f16 wls[128 * 68];   // 17408 B Wh K-chunk; aliased ls below
    __shared__ float st[256];                     // 1024 B channel sums/sqsums
    float* ls = (float*)wls;                      // [16][132] f32 epilogue stage
    const int tid = threadIdx.x;
    const int brow = blockIdx.x * 16;             // NN = 16*3125 exactly: no guards

    // ---- gather phase: node i = tid>>4, channel octet q = tid&15 ----
    {
        int i = tid >> 4, q = tid & 15;
        int n = brow + i;
        int ri = rowinfo[n];
        int dg = ri >> 16;
        int r0 = (n >> 8) * CAP + (ri & 0xffff);
        int r1 = r0 + dg;
        const f16* hq = hin + q * 8;
        float s[8] = {0.f, 0.f, 0.f, 0.f, 0.f, 0.f, 0.f, 0.f};
        int e = r0;
        for (; e + 4 <= r1; e += 4) {
            int i0 = perm[e], i1 = perm[e + 1], i2 = perm[e + 2], i3 = perm[e + 3];
            f16x8 v0 = *(const f16x8*)(hq + (size_t)i0 * HD);
            f16x8 v1 = *(const f16x8*)(hq + (size_t)i1 * HD);
            f16x8 v2 = *(const f16x8*)(hq + (size_t)i2 * HD);
            f16x8 v3 = *(const f16x8*)(hq + (size_t)i3 * HD);
#pragma unroll
            for (int j = 0; j < 8; ++j)
                s[j] += ((float)v0[j] + (float)v1[j]) + ((float)v2[j] + (float)v3[j]);
        }
        if (e + 2 <= r1) {
            int i0 = perm[e], i1 = perm[e + 1];
            f16x8 v0 = *(const f16x8*)(hq + (size_t)i0 * HD);
            f16x8 v1 = *(const f16x8*)(hq + (size_t)i1 * HD);
#pragma unroll
            for (int j = 0; j < 8; ++j) s[j] += (float)v0[j] + (float)v1[j];
            e += 2;
        }
        if (e < r1) {
            int i0 = perm[e];
            f16x8 v0 = *(const f16x8*)(hq + (size_t)i0 * HD);
#pragma unroll
            for (int j = 0; j < 8; ++j) s[j] += (float)v0[j];
        }
        if (dg > 0) {
            float rr = 1.0f / (float)dg;
#pragma unroll
            for (int j = 0; j < 8; ++j) s[j] *= rr;
        } else if (statsPrev) {
            // deg-0 sentinel: -sh/sc so the BN-folded GEMM contribution is exactly 0
#pragma unroll
            for (int j = 0; j < 8; ++j) {
                float sc, sh;
                bn_affine(statsPrev, q * 8 + j, gamP, betP, &sc, &sh);
                s[j] = (sc != 0.f) ? (-sh / sc) : 0.f;
            }
        }  // layer 0: sentinel is 0 (identity affine), s[] already 0
        f16x8 o;
#pragma unroll
        for (int j = 0; j < 8; ++j) o[j] = (f16)s[j];
        *(f16x8*)&alds[i * 136 + q * 8] = o;
    }

    const int lane = tid & 63, wave = tid >> 6;
    const int lm = lane & 15, kg = lane >> 4;
    const f16* hrow = hin + (size_t)(brow + lm) * HD;  // self-half K source
    f32x4 acc0 = (f32x4){0.f, 0.f, 0.f, 0.f};
    f32x4 acc1 = (f32x4){0.f, 0.f, 0.f, 0.f};
    __syncthreads();  // alds ready

    // ---- GEMM: M=16, N=128, K=256 in four 64-wide K-chunks ----
#pragma unroll
    for (int kc = 0; kc < 4; ++kc) {
        // stage Wh[0..127][kc*64..+64) -> wls[128][68]
#pragma unroll
        for (int it = 0; it < 4; ++it) {
            int slot = tid + it * 256;
            int r = slot >> 3, c = slot & 7;
            *(f16x8*)&wls[r * 68 + c * 8] =
                *(const f16x8*)(Wh + (size_t)r * 256 + kc * 64 + c * 8);
        }
        __syncthreads();
#pragma unroll
        for (int f = 0; f < 2; ++f) {  // two K=32 fragments per chunk
            f16x8 av;
            if (kc < 2)  // agg half from LDS
                av = *(const f16x8*)&alds[lm * 136 + kc * 64 + f * 32 + kg * 8];
            else         // self half from global (L2-warm contiguous rows)
                av = *(const f16x8*)(hrow + (kc - 2) * 64 + f * 32 + kg * 8);
            f16x8 b0 = *(const f16x8*)&wls[(wave * 32 + lm) * 68 + f * 32 + kg * 8];
            f16x8 b1 = *(const f16x8*)&wls[(wave * 32 + 16 + lm) * 68 + f * 32 + kg * 8];
            acc0 = __builtin_amdgcn_mfma_f32_16x16x32_f16(av, b0, acc0, 0, 0, 0);
            acc1 = __builtin_amdgcn_mfma_f32_16x16x32_f16(av, b1, acc1, 0, 0, 0);
        }
        __syncthreads();  // wls reads done before next stage (and before ls alias)
    }

    // ---- epilogue: bias+ReLU, stats, stage via ls, coalesced store ----
#pragma unroll
    for (int t = 0; t < 2; ++t) {
        int ch = (wave * 2 + t) * 16 + lm;  // output channel (C col = lane&15)
        float bs = bias2[ch];
        f32x4 A = t ? acc1 : acc0;
        float s = 0.f, sq = 0.f;
#pragma unroll
        for (int r = 0; r < 4; ++r) {       // C row = kg*4 + r
            float y = fmaxf(A[r] + bs, 0.f);
            ls[(kg * 4 + r) * 132 + ch] = y;
            s += y; sq += y * y;
        }
        s += __shfl_xor(s, 16); s += __shfl_xor(s, 32);
        sq += __shfl_xor(sq, 16); sq += __shfl_xor(sq, 32);
        if (kg == 0) { st[ch] = s; st[128 + ch] = sq; }  // single writer per slot
    }
    __syncthreads();
    atomicAdd(&statsN[(blockIdx.x & (NREP - 1)) * 256 + tid], st[tid]);
    {
        int r = tid >> 4, oc = tid & 15;
        const float* p = &ls[r * 132 + oc * 8];
        f16x8 o;
#pragma unroll
        for (int j = 0; j < 8; ++j) o[j] = (f16)p[j];
        *(f16x8*)(yout + (size_t)(brow + r) * HD + oc * 8) = o;
    }
}

// ---------------- pooling: 8 splits/group (512 blocks; keeps CUs saturated) ----------
__global__ __launch_bounds__(256)
void pool2_kernel(const f16* __restrict__ hf, const int* __restrict__ gb,
                  float* __restrict__ pooled) {
    __shared__ float red[16 * 128];
    int g = blockIdx.x >> 3, sp = blockIdx.x & 7;
    int s = gb[g], e = gb[g + 1];
    int q = threadIdx.x & 15, r = threadIdx.x >> 4;
    float a[8] = {0.f, 0.f, 0.f, 0.f, 0.f, 0.f, 0.f, 0.f};
    for (int n = s + sp * 16 + r; n < e; n += 128) {
        f16x8 v = *(const f16x8*)(hf + (size_t)n * HD + q * 8);
#pragma unroll
        for (int j = 0; j < 8; ++j) a[j] += (float)v[j];
    }
#pragma unroll
    for (int j = 0; j < 8; ++j) red[r * 128 + q * 8 + j] = a[j];
    __syncthreads();
    for (int stp = 8; stp >= 1; stp >>= 1) {
        if (r < stp) {
#pragma unroll
            for (int j = 0; j < 8; ++j)
                red[r * 128 + q * 8 + j] += red[(r + stp) * 128 + q * 8 + j];
        }
        __syncthreads();
    }
    if (r == 0) {
#pragma unroll
        for (int j = 0; j < 8; ++j) atomicAdd(&pooled[g * HD + q * 8 + j], red[q * 8 + j]);
    }
}

// ---------------- head: layer-3 BN (from replicated stats) + dot + sigmoid ----------
__global__ void head_kernel(const float* __restrict__ pooled, const int* __restrict__ gb,
                            const float* __restrict__ stats3, const float* __restrict__ gam3,
                            const float* __restrict__ bet3, const float* __restrict__ fcw,
                            const float* __restrict__ fcb, float* __restrict__ out) {
    __shared__ float red[2];
    int g = blockIdx.x, c = threadIdx.x;  // 128 threads
    float sc, sh;
    bn_affine(stats3, c, gam3, bet3, &sc, &sh);
    float cnt = (float)(gb[g + 1] - gb[g]);
    float v = (pooled[g * HD + c] * sc + cnt * sh) * fcw[c];
#pragma unroll
    for (int o = 32; o > 0; o >>= 1) v += __shfl_xor(v, o);
    if ((c & 63) == 0) red[c >> 6] = v;
    __syncthreads();
    if (c == 0) {
        float s = red[0] + red[1] + fcb[0];
        out[g] = 1.0f / (1.0f + expf(-s));
    }
}

extern "C" void kernel_launch(void* const* d_in, const int* in_sizes, int n_in,
                              void* d_out, int out_size, void* d_ws, size_t ws_size,
                              hipStream_t stream) {
    const float* x     = (const float*)d_in[0];
    const int*   ei    = (const int*)d_in[1];
    const int*   src   = ei;
    const int*   dst   = ei + NE;
    const int*   batch = (const int*)d_in[3];
    const float* Wl    = (const float*)d_in[4];
    const float* bl    = (const float*)d_in[5];
    const float* Wr    = (const float*)d_in[6];
    const float* gamma = (const float*)d_in[7];
    const float* beta  = (const float*)d_in[8];
    const float* fcw   = (const float*)d_in[9];
    const float* fcb   = (const float*)d_in[10];
    float* out = (float*)d_out;

    f16* hf0  = (f16*)d_ws;                       // [NN][128] fp16 (x converted)
    f16* hfA  = hf0 + (size_t)NN * HD;
    f16* hfB  = hfA + (size_t)NN * HD;
    f16* Wh   = hfB + (size_t)NN * HD;            // [128][256] fp16
    float* bias2 = (float*)(Wh + 128 * 256);      // 128
    // ---- contiguous zero zone (single memset) ----
    float* zero0    = bias2 + HD;
    float* statsRaw = zero0;                      // 3 layers x NREP x 256
    float* pooled   = statsRaw + 3 * NREP * 256;  // NG*HD
    int* bcur  = (int*)(pooled + NG * HD);        // NB relative cursors
    size_t zero_bytes = (3 * NREP * 256 + NG * HD) * sizeof(float) + NB * sizeof(int);
    // ---- rest ----
    int* rowinfo = bcur + NB;                     // NN
    int* gb      = rowinfo + NN;                  // NG+1
    int* perm    = gb + NG + 1;                   // NB*CAP (padded CSR)
    // staging ALIASES hfB: live window (scatcvt->buckbuild) ends before hfB's
    // first write (fused layer 1). R7-passed aliasing.
    unsigned* staging = (unsigned*)hfB;           // NB*CAP (6.42MB < 12.8MB)

    hipMemsetAsync(zero0, 0, zero_bytes, stream);

    scatcvt_kernel<<<NCNT + GATHB, 256, 0, stream>>>(x, src, dst, batch, bcur,
                                                     staging, hf0, gb);
    buckbuild_kernel<<<NB + 128, 256, 0, stream>>>(staging, bcur, rowinfo, perm,
                                                   Wl, Wr, bl, Wh, bias2);

    const f16* hin = hf0;
    f16* houts[3] = {hfA, hfB, hfA};
    for (int l = 0; l < NL; ++l) {
        const float* stP = (l == 0) ? nullptr : (statsRaw + (size_t)(l - 1) * NREP * 256);
        const float* gP  = gamma + (l == 0 ? 0 : (l - 1)) * HD;
        const float* bP  = beta + (l == 0 ? 0 : (l - 1)) * HD;
        if (l > 0)  // stream-ordered weight prep (layer l-1 stats complete)
            wprep_kernel<<<128, 256, 0, stream>>>(stP, gP, bP, Wl + (size_t)l * HD * HD,
                                                  Wr + (size_t)l * HD * HD, bl + l * HD,
                                                  Wh, bias2);
        fused16_kernel<<<FUSEB, 256, 0, stream>>>(
            hin, rowinfo, perm, stP, gP, bP, Wh, bias2,
            houts[l], statsRaw + (size_t)l * NREP * 256);
        hin = houts[l];
    }
    pool2_kernel<<<NG * 8, 256, 0, stream>>>(hfA, gb, pooled);
    head_kernel<<<NG, 128, 0, stream>>>(pooled, gb, statsRaw + 2 * NREP * 256,
                                        gamma + 2 * HD, beta + 2 * HD, fcw, fcb, out);
}

// Round 11
// 263.570 us; speedup vs baseline: 1.1393x; 1.0233x over previous
//
#include <hip/hip_runtime.h>
#include <math.h>

#define NN 50000
#define NE 800000
#define HD 128
#define NL 3
#define NG 64
#define BN_EPS 1e-5f
#define NB 196   // dst buckets of 256 nodes
#define EPB 4096 // edges per block in bucket scatter
#define NCNT ((NE + EPB - 1) / EPB)     // 196 scatter blocks
#define CAP 8192 // fixed bucket capacity (mean 4096 + 64 sigma)
#define NREP 32  // stats replicas (TCC same-address contention /32)
#define GATHB ((NN * 16) / 256)         // 3125 cvt blocks (exact)
#define FUSEB (NN / 16)                 // 3125 fused tiles (NN = 16*3125 exactly)

typedef _Float16 f16;
typedef __attribute__((ext_vector_type(8))) _Float16 f16x8;
typedef __attribute__((ext_vector_type(4))) float f32x4;

// BN affine from replicated raw sums
__device__ __forceinline__ void bn_affine(const float* __restrict__ sR, int c,
                                          const float* __restrict__ gam,
                                          const float* __restrict__ bet,
                                          float* sc, float* sh) {
    float s0 = 0.f, s1 = 0.f;
#pragma unroll 8
    for (int r = 0; r < NREP; ++r) {
        s0 += sR[r * 256 + c];
        s1 += sR[r * 256 + 128 + c];
    }
    float invN = 1.0f / (float)NN;
    float mu = s0 * invN;
    float var = s1 * invN - mu * mu;
    var = var < 0.f ? 0.f : var;
    float s = rsqrtf(var + BN_EPS) * gam[c];
    *sc = s;
    *sh = bet[c] - mu * s;
}

// weight prep body: BN-folded Wh (fp16) + folded bias2. One block per output ch j.
__device__ __forceinline__ void wprep_body(int j, int k, float* red,
                                           const float* __restrict__ statsPrev,
                                           const float* __restrict__ gamP,
                                           const float* __restrict__ betP,
                                           const float* __restrict__ Wl,
                                           const float* __restrict__ Wr,
                                           const float* __restrict__ bl,
                                           f16* __restrict__ Wh,
                                           float* __restrict__ bias2) {
    float scp = 1.0f, shp = 0.0f;
    if (statsPrev) bn_affine(statsPrev, k & 127, gamP, betP, &scp, &shp);
    float w = (k < HD) ? Wl[j * HD + k] : Wr[j * HD + (k - HD)];
    Wh[j * 256 + k] = (f16)(w * scp);
    red[k] = shp * w;
    __syncthreads();
    for (int s = 128; s > 0; s >>= 1) {
        if (k < s) red[k] += red[k + s];
        __syncthreads();
    }
    if (k == 0) bias2[j] = bl[j] + red[0];
}

// ================= fused scatter (fixed-capacity buckets) + cvt + gb =================
__global__ __launch_bounds__(256)
void scatcvt_kernel(const float* __restrict__ x, const int* __restrict__ src,
                    const int* __restrict__ dst, const int* __restrict__ batch,
                    int* __restrict__ bcur, unsigned* __restrict__ staging,
                    f16* __restrict__ hf, int* __restrict__ gb) {
    if (blockIdx.x < NCNT) {
        __shared__ int h[NB];
        __shared__ int rbase[NB];
        for (int i = threadIdx.x; i < NB; i += 256) h[i] = 0;
        __syncthreads();
        int base = blockIdx.x * EPB;
#pragma unroll
        for (int it = 0; it < EPB / 256; ++it) {
            int e = base + it * 256 + threadIdx.x;
            if (e < NE) atomicAdd(&h[dst[e] >> 8], 1);
        }
        __syncthreads();
        for (int i = threadIdx.x; i < NB; i += 256) {
            rbase[i] = h[i] ? atomicAdd(&bcur[i], h[i]) : 0;
            h[i] = 0;
        }
        __syncthreads();
#pragma unroll
        for (int it = 0; it < EPB / 256; ++it) {
            int e = base + it * 256 + threadIdx.x;
            if (e < NE) {
                int d = dst[e];
                int k = d >> 8;
                int p = rbase[k] + atomicAdd(&h[k], 1);
                if (p < CAP)  // capacity guard (statistically impossible to trip)
                    staging[(size_t)k * CAP + p] = ((unsigned)d << 16) | (unsigned)src[e];
            }
        }
    } else {
        // ---- cvt block: fp32 -> fp16 row conversion + group-boundary table ----
        int t = (blockIdx.x - NCNT) * 256 + threadIdx.x;  // t < NN*16 exactly
        if (t < NN) {
            int b = batch[t];
            int bp = (t == 0) ? -1 : batch[t - 1];
            for (int g = bp + 1; g <= b; ++g) gb[g] = t;
            if (t == NN - 1)
                for (int g = b + 1; g <= NG; ++g) gb[g] = NN;
        }
        int n = t >> 4, q = t & 15;
        float4 v0 = ((const float4*)x)[n * 32 + q * 2];
        float4 v1 = ((const float4*)x)[n * 32 + q * 2 + 1];
        f16x8 o;
        o[0] = (f16)v0.x; o[1] = (f16)v0.y; o[2] = (f16)v0.z; o[3] = (f16)v0.w;
        o[4] = (f16)v1.x; o[5] = (f16)v1.y; o[6] = (f16)v1.z; o[7] = (f16)v1.w;
        *(f16x8*)(hf + (size_t)n * HD + q * 8) = o;
    }
}

// ===== per-bucket build (blocks 0..NB-1) + layer-0 weight prep (blocks NB..NB+127) =====
__global__ __launch_bounds__(256)
void buckbuild_kernel(const unsigned* __restrict__ staging, const int* __restrict__ bcur,
                      int* __restrict__ rowinfo, int* __restrict__ perm,
                      const float* __restrict__ Wl0, const float* __restrict__ Wr0,
                      const float* __restrict__ bl0, f16* __restrict__ Wh,
                      float* __restrict__ bias2) {
    __shared__ __align__(16) char sm[2048 + 2 * CAP];
    const int tid = threadIdx.x;
    if (blockIdx.x >= NB) {  // layer-0 weight prep rides along (no stats dependency)
        wprep_body(blockIdx.x - NB, tid, (float*)sm, nullptr, nullptr, nullptr,
                   Wl0, Wr0, bl0, Wh, bias2);
        return;
    }
    int* cnt = (int*)sm;
    int* pre = cnt + 256;
    unsigned short* lperm = (unsigned short*)(pre + 256);
    const int k = blockIdx.x;
    const int base = k * CAP;
    int size = bcur[k];
    if (size > CAP) size = CAP;
    cnt[tid] = 0;
    __syncthreads();
    for (int i = tid; i < size; i += 256)
        atomicAdd(&cnt[(int)(staging[base + i] >> 16) - k * 256], 1);
    __syncthreads();
    int v = cnt[tid];
    pre[tid] = v;
    __syncthreads();
    for (int off = 1; off < 256; off <<= 1) {
        int t2 = (tid >= off) ? pre[tid - off] : 0;
        __syncthreads();
        pre[tid] += t2;
        __syncthreads();
    }
    int excl = pre[tid] - v;
    int n = k * 256 + tid;
    if (n < NN) rowinfo[n] = excl | (v << 16);
    cnt[tid] = excl;  // reuse as scatter cursors
    __syncthreads();
    for (int i = tid; i < size; i += 256) {
        unsigned w = staging[base + i];
        int dl = (int)(w >> 16) - k * 256;
        int p = atomicAdd(&cnt[dl], 1);
        lperm[p] = (unsigned short)(w & 0xffffu);  // src < 65536 (NN=50000)
    }
    __syncthreads();
    for (int i = tid; i < size; i += 256) perm[base + i] = (int)lperm[i];
}

// ================= standalone weight prep for layers 1,2 (needs prev stats) =================
__global__ __launch_bounds__(256)
void wprep_kernel(const float* __restrict__ statsPrev, const float* __restrict__ gamP,
                  const float* __restrict__ betP, const float* __restrict__ Wl,
                  const float* __restrict__ Wr, const float* __restrict__ bl,
                  f16* __restrict__ Wh, float* __restrict__ bias2) {
    __shared__ float red[256];
    wprep_body(blockIdx.x, threadIdx.x, red, statsPrev, gamP, betP, Wl, Wr, bl, Wh, bias2);
}

// ===== fused16: gather 16 nodes -> M=16 MFMA GEMM; lastl pools in epilogue =====
// 3125 blocks (= split-gather grid). LDS 22784B -> 7 blocks/CU; GEMM (no fabric
// traffic) hides inside the fabric-bound gather of co-resident blocks.
__global__ __launch_bounds__(256, 7)
void fused16_kernel(const f16* __restrict__ hin, const int* __restrict__ rowinfo,
                    const int* __restrict__ perm, const float* __restrict__ statsPrev,
                    const float* __restrict__ gamP, const float* __restrict__ betP,
                    const f16* __restrict__ Wh, const float* __restrict__ bias2,
                    f16* __restrict__ yout, float* __restrict__ statsN,
                    const int* __restrict__ batch, float* __restrict__ pooledR,
                    int lastl) {
    __shared__ __align__(16) f16 alds[16 * 136];  // 4352 B agg tile (stride 136 f16)
    __shared__ __align__(16) f16 wls[128 * 68];   // 17408 B Wh K-chunk; aliased ls below
    __shared__ float st[256];                     // 1024 B channel sums/sqsums
    float* ls = (float*)wls;                      // [16][132] f32 epilogue stage
    const int tid = threadIdx.x;
    const int brow = blockIdx.x * 16;             // NN = 16*3125 exactly: no guards

    // ---- gather phase: node i = tid>>4, channel octet q = tid&15 ----
    {
        int i = tid >> 4, q = tid & 15;
        int n = brow + i;
        int ri = rowinfo[n];
        int dg = ri >> 16;
        int r0 = (n >> 8) * CAP + (ri & 0xffff);
        int r1 = r0 + dg;
        const f16* hq = hin + q * 8;
        float s[8] = {0.f, 0.f, 0.f, 0.f, 0.f, 0.f, 0.f, 0.f};
        int e = r0;
        for (; e + 4 <= r1; e += 4) {
            int i0 = perm[e], i1 = perm[e + 1], i2 = perm[e + 2], i3 = perm[e + 3];
            f16x8 v0 = *(const f16x8*)(hq + (size_t)i0 * HD);
            f16x8 v1 = *(const f16x8*)(hq + (size_t)i1 * HD);
            f16x8 v2 = *(const f16x8*)(hq + (size_t)i2 * HD);
            f16x8 v3 = *(const f16x8*)(hq + (size_t)i3 * HD);
#pragma unroll
            for (int j = 0; j < 8; ++j)
                s[j] += ((float)v0[j] + (float)v1[j]) + ((float)v2[j] + (float)v3[j]);
        }
        if (e + 2 <= r1) {
            int i0 = perm[e], i1 = perm[e + 1];
            f16x8 v0 = *(const f16x8*)(hq + (size_t)i0 * HD);
            f16x8 v1 = *(const f16x8*)(hq + (size_t)i1 * HD);
#pragma unroll
            for (int j = 0; j < 8; ++j) s[j] += (float)v0[j] + (float)v1[j];
            e += 2;
        }
        if (e < r1) {
            int i0 = perm[e];
            f16x8 v0 = *(const f16x8*)(hq + (size_t)i0 * HD);
#pragma unroll
            for (int j = 0; j < 8; ++j) s[j] += (float)v0[j];
        }
        if (dg > 0) {
            float rr = 1.0f / (float)dg;
#pragma unroll
            for (int j = 0; j < 8; ++j) s[j] *= rr;
        } else if (statsPrev) {
            // deg-0 sentinel: -sh/sc so the BN-folded GEMM contribution is exactly 0
#pragma unroll
            for (int j = 0; j < 8; ++j) {
                float sc, sh;
                bn_affine(statsPrev, q * 8 + j, gamP, betP, &sc, &sh);
                s[j] = (sc != 0.f) ? (-sh / sc) : 0.f;
            }
        }  // layer 0: sentinel is 0 (identity affine), s[] already 0
        f16x8 o;
#pragma unroll
        for (int j = 0; j < 8; ++j) o[j] = (f16)s[j];
        *(f16x8*)&alds[i * 136 + q * 8] = o;
    }

    const int lane = tid & 63, wave = tid >> 6;
    const int lm = lane & 15, kg = lane >> 4;
    const f16* hrow = hin + (size_t)(brow + lm) * HD;  // self-half K source
    f32x4 acc0 = (f32x4){0.f, 0.f, 0.f, 0.f};
    f32x4 acc1 = (f32x4){0.f, 0.f, 0.f, 0.f};
    __syncthreads();  // alds ready

    // ---- GEMM: M=16, N=128, K=256 in four 64-wide K-chunks ----
#pragma unroll
    for (int kc = 0; kc < 4; ++kc) {
        // stage Wh[0..127][kc*64..+64) -> wls[128][68]
#pragma unroll
        for (int it = 0; it < 4; ++it) {
            int slot = tid + it * 256;
            int r = slot >> 3, c = slot & 7;
            *(f16x8*)&wls[r * 68 + c * 8] =
                *(const f16x8*)(Wh + (size_t)r * 256 + kc * 64 + c * 8);
        }
        __syncthreads();
#pragma unroll
        for (int f = 0; f < 2; ++f) {  // two K=32 fragments per chunk
            f16x8 av;
            if (kc < 2)  // agg half from LDS
                av = *(const f16x8*)&alds[lm * 136 + kc * 64 + f * 32 + kg * 8];
            else         // self half from global (L2-warm contiguous rows)
                av = *(const f16x8*)(hrow + (kc - 2) * 64 + f * 32 + kg * 8);
            f16x8 b0 = *(const f16x8*)&wls[(wave * 32 + lm) * 68 + f * 32 + kg * 8];
            f16x8 b1 = *(const f16x8*)&wls[(wave * 32 + 16 + lm) * 68 + f * 32 + kg * 8];
            acc0 = __builtin_amdgcn_mfma_f32_16x16x32_f16(av, b0, acc0, 0, 0, 0);
            acc1 = __builtin_amdgcn_mfma_f32_16x16x32_f16(av, b1, acc1, 0, 0, 0);
        }
        __syncthreads();  // wls reads done before next stage (and before ls alias)
    }

    // ---- epilogue: bias+ReLU, stats, stage via ls ----
#pragma unroll
    for (int t = 0; t < 2; ++t) {
        int ch = (wave * 2 + t) * 16 + lm;  // output channel (C col = lane&15)
        float bs = bias2[ch];
        f32x4 A = t ? acc1 : acc0;
        float s = 0.f, sq = 0.f;
#pragma unroll
        for (int r = 0; r < 4; ++r) {       // C row = kg*4 + r
            float y = fmaxf(A[r] + bs, 0.f);
            ls[(kg * 4 + r) * 132 + ch] = y;
            s += y; sq += y * y;
        }
        s += __shfl_xor(s, 16); s += __shfl_xor(s, 32);
        sq += __shfl_xor(sq, 16); sq += __shfl_xor(sq, 32);
        if (kg == 0) { st[ch] = s; st[128 + ch] = sq; }  // single writer per slot
    }
    __syncthreads();
    atomicAdd(&statsN[(blockIdx.x & (NREP - 1)) * 256 + tid], st[tid]);
    if (!lastl) {
        int r = tid >> 4, oc = tid & 15;
        const float* p = &ls[r * 132 + oc * 8];
        f16x8 o;
#pragma unroll
        for (int j = 0; j < 8; ++j) o[j] = (f16)p[j];
        *(f16x8*)(yout + (size_t)(brow + r) * HD + oc * 8) = o;
    } else {
        // ---- pooling epilogue: output used only for group-sum -> never materialize ----
        float* pr = pooledR + (size_t)(blockIdx.x & 7) * NG * HD;
        int gmin = batch[brow], gmax = batch[brow + 15];
        if (gmin == gmax) {
            // st[c] == sum of this block's 16 rows (single group)
            if (tid < HD) atomicAdd(&pr[gmin * HD + tid], st[tid]);
        } else {
            // boundary (~2% of blocks): block spans exactly 2 groups (min group >> 16)
            int gg = tid >> 7, ch = tid & 127;
            int g = gmin + gg;
            if (g <= gmax) {
                float s = 0.f;
#pragma unroll
                for (int r = 0; r < 16; ++r)
                    if (batch[brow + r] == g) s += ls[r * 132 + ch];
                atomicAdd(&pr[g * HD + ch], s);
            }
        }
    }
}

// ---------------- head: layer-3 BN (replicated stats) + replica-summed pool + sigmoid ----
__global__ void head_kernel(const float* __restrict__ pooledR, const int* __restrict__ gb,
                            const float* __restrict__ stats3, const float* __restrict__ gam3,
                            const float* __restrict__ bet3, const float* __restrict__ fcw,
                            const float* __restrict__ fcb, float* __restrict__ out) {
    __shared__ float red[2];
    int g = blockIdx.x, c = threadIdx.x;  // 128 threads
    float sc, sh;
    bn_affine(stats3, c, gam3, bet3, &sc, &sh);
    float p = 0.f;
#pragma unroll
    for (int r = 0; r < 8; ++r) p += pooledR[(size_t)r * NG * HD + g * HD + c];
    float cnt = (float)(gb[g + 1] - gb[g]);
    float v = (p * sc + cnt * sh) * fcw[c];
#pragma unroll
    for (int o = 32; o > 0; o >>= 1) v += __shfl_xor(v, o);
    if ((c & 63) == 0) red[c >> 6] = v;
    __syncthreads();
    if (c == 0) {
        float s = red[0] + red[1] + fcb[0];
        out[g] = 1.0f / (1.0f + expf(-s));
    }
}

extern "C" void kernel_launch(void* const* d_in, const int* in_sizes, int n_in,
                              void* d_out, int out_size, void* d_ws, size_t ws_size,
                              hipStream_t stream) {
    const float* x     = (const float*)d_in[0];
    const int*   ei    = (const int*)d_in[1];
    const int*   src   = ei;
    const int*   dst   = ei + NE;
    const int*   batch = (const int*)d_in[3];
    const float* Wl    = (const float*)d_in[4];
    const float* bl    = (const float*)d_in[5];
    const float* Wr    = (const float*)d_in[6];
    const float* gamma = (const float*)d_in[7];
    const float* beta  = (const float*)d_in[8];
    const float* fcw   = (const float*)d_in[9];
    const float* fcb   = (const float*)d_in[10];
    float* out = (float*)d_out;

    f16* hf0  = (f16*)d_ws;                       // [NN][128] fp16 (x converted)
    f16* hfA  = hf0 + (size_t)NN * HD;
    f16* hfB  = hfA + (size_t)NN * HD;
    f16* Wh   = hfB + (size_t)NN * HD;            // [128][256] fp16
    float* bias2 = (float*)(Wh + 128 * 256);      // 128
    // ---- contiguous zero zone (single memset) ----
    float* zero0    = bias2 + HD;
    float* statsRaw = zero0;                      // 3 layers x NREP x 256
    float* pooledR  = statsRaw + 3 * NREP * 256;  // 8 replicas x NG x HD
    int* bcur  = (int*)(pooledR + 8 * NG * HD);   // NB relative cursors
    size_t zero_bytes = (3 * NREP * 256 + 8 * NG * HD) * sizeof(float) + NB * sizeof(int);
    // ---- rest ----
    int* rowinfo = bcur + NB;                     // NN
    int* gb      = rowinfo + NN;                  // NG+1
    int* perm    = gb + NG + 1;                   // NB*CAP (padded CSR)
    // staging ALIASES hfB: live window (scatcvt->buckbuild) ends before hfB's
    // first write (fused layer 1). R7/R10-proven aliasing.
    unsigned* staging = (unsigned*)hfB;           // NB*CAP (6.42MB < 12.8MB)

    hipMemsetAsync(zero0, 0, zero_bytes, stream);

    scatcvt_kernel<<<NCNT + GATHB, 256, 0, stream>>>(x, src, dst, batch, bcur,
                                                     staging, hf0, gb);
    buckbuild_kernel<<<NB + 128, 256, 0, stream>>>(staging, bcur, rowinfo, perm,
                                                   Wl, Wr, bl, Wh, bias2);

    const f16* hin = hf0;
    f16* houts[3] = {hfA, hfB, hfA};  // L2 output ignored (pooled in epilogue)
    for (int l = 0; l < NL; ++l) {
        const float* stP = (l == 0) ? nullptr : (statsRaw + (size_t)(l - 1) * NREP * 256);
        const float* gP  = gamma + (l == 0 ? 0 : (l - 1)) * HD;
        const float* bP  = beta + (l == 0 ? 0 : (l - 1)) * HD;
        if (l > 0)  // stream-ordered weight prep (layer l-1 stats complete)
            wprep_kernel<<<128, 256, 0, stream>>>(stP, gP, bP, Wl + (size_t)l * HD * HD,
                                                  Wr + (size_t)l * HD * HD, bl + l * HD,
                                                  Wh, bias2);
        fused16_kernel<<<FUSEB, 256, 0, stream>>>(
            hin, rowinfo, perm, stP, gP, bP, Wh, bias2,
            houts[l], statsRaw + (size_t)l * NREP * 256,
            batch, pooledR, (l == NL - 1) ? 1 : 0);
        hin = houts[l];
    }
    head_kernel<<<NG, 128, 0, stream>>>(pooledR, gb, statsRaw + 2 * NREP * 256,
                                        gamma + 2 * HD, beta + 2 * HD, fcw, fcb, out);
}